// Round 2
// baseline (1695.412 us; speedup 1.0000x reference)
//
#include <hip/hip_runtime.h>
#include <hip/hip_bf16.h>
#include <math.h>

#define QN 128
#define TN 48
#define CN 64
#define HN 96
#define WN 128
#define DN 128
#define KK 49
#define IN_DIM 276
#define NROWS (QN*TN)

typedef __hip_bfloat16 bf16;

__device__ inline float fixnan(float x){ return (x == x && fabsf(x) < 1e30f) ? x : 0.f; }

// MODE 0: buffers are float32. MODE 1: buffers are bf16.
template<int MODE> __device__ inline float ld(const void* p, size_t i){
  if constexpr (MODE == 0) return ((const float*)p)[i];
  else {
    unsigned int u = ((const unsigned short*)p)[i];
    return __uint_as_float(u << 16);
  }
}

__device__ inline float waveReduceSum(float v){
  #pragma unroll
  for (int off = 32; off > 0; off >>= 1) v += __shfl_xor(v, off, 64);
  return v;
}

__device__ inline float gelu_exact(float x){
  return 0.5f * x * (1.f + erff(x * 0.70710678118654752440f));
}

__device__ inline float decode_stride(const void* p){
  int iv = *(const int*)p;
  if (iv >= 1 && iv <= (1 << 20)) return (float)iv;
  float fv = __int_as_float(iv);
  if (fv == fv && fv >= 0.25f && fv <= 1048576.f) return fv;
  unsigned int lo = ((unsigned int)(*(const unsigned short*)p)) << 16;
  float bv = __uint_as_float(lo);
  if (bv == bv && bv >= 0.25f && bv <= 1048576.f) return bv;
  return 4.f;
}

// ---- dtype sniffer on query_features (8192 ~N(0,1) values) ----
__global__ __launch_bounds__(256) void k_sniff(const unsigned short* __restrict__ q,
                                               int* __restrict__ flag){
  __shared__ int cnt;
  if (threadIdx.x == 0) cnt = 0;
  __syncthreads();
  int good = 0;
  for (int i = threadIdx.x; i < 8192; i += 256){
    float v = __uint_as_float(((unsigned int)q[i]) << 16);
    float a = fabsf(v);
    if (a > 1e-3f && a < 30.f) good++;
  }
  atomicAdd(&cnt, good);
  __syncthreads();
  if (threadIdx.x == 0) flag[0] = (cnt > 6500) ? 1 : 0;  // 1 = bf16 data
}

// ---- init ----
template<int MODE>
__global__ __launch_bounds__(256) void k_init(const int* __restrict__ mf,
                                              const void* __restrict__ ct,
                                              float* __restrict__ tracks,
                                              float* __restrict__ vis_sum){
  if (mf[0] != MODE) return;
  int i = blockIdx.x * 256 + threadIdx.x;
  if (i < NROWS){
    tracks[2*i]   = fixnan(ld<MODE>(ct, 2*i));
    tracks[2*i+1] = fixnan(ld<MODE>(ct, 2*i+1));
    vis_sum[i] = 0.f;
  }
}

// ---- local correlation: one wave per (q,t) ----
template<int MODE>
__global__ __launch_bounds__(64) void k_corr(const int* __restrict__ mf,
                                             const void* __restrict__ fmap,
                                             const void* __restrict__ query,
                                             const float* __restrict__ tracks,
                                             const void* __restrict__ stride_p,
                                             float* __restrict__ X){
  if (mf[0] != MODE) return;
  int blk = blockIdx.x;            // q*T + t
  int q = blk / TN, t = blk % TN;
  int lane = threadIdx.x;
  __shared__ float qv[CN];
  __shared__ float dots[8][8];
  qv[lane] = ld<MODE>(query, q*CN + lane);
  __syncthreads();

  float fs = decode_stride(stride_p);
  float px = fixnan(tracks[2*blk]   / fs);
  float py = fixnan(tracks[2*blk+1] / fs);
  px = fminf(fmaxf(px, -1e6f), 1e6f);
  py = fminf(fmaxf(py, -1e6f), 1e6f);
  float fx0 = floorf(px), fy0 = floorf(py);
  float dx = px - fx0, dy = py - fy0;
  int bx = (int)fx0, by = (int)fy0;

  int j = lane >> 3, i = lane & 7;     // tap grid 8x8, offsets -3..+4
  int xi = bx + i - 3, yi = by + j - 3;
  float dot = 0.f;
  if (xi >= 0 && xi < WN && yi >= 0 && yi < HN){
    size_t base = (size_t)t*CN*HN*WN + (size_t)yi*WN + xi;
    #pragma unroll 8
    for (int c = 0; c < CN; ++c)
      dot += qv[c] * ld<MODE>(fmap, base + (size_t)c*HN*WN);
  }
  dots[j][i] = dot;
  __syncthreads();

  if (lane < KK){
    int oy = lane / 7, ox = lane % 7;
    float w00 = (1.f-dx)*(1.f-dy), w01 = dx*(1.f-dy);
    float w10 = (1.f-dx)*dy,       w11 = dx*dy;
    float v = w00*dots[oy][ox]   + w01*dots[oy][ox+1]
            + w10*dots[oy+1][ox] + w11*dots[oy+1][ox+1];
    X[(size_t)blk*IN_DIM + lane] = fixnan(v);
  }
}

// ---- fourier pos-enc + hidden copy into X ----
template<int MODE>
__global__ __launch_bounds__(128) void k_assemble(const int* __restrict__ mf,
                                                  const float* __restrict__ tracks,
                                                  const float* __restrict__ hd,
                                                  float* __restrict__ X){
  if (mf[0] != MODE) return;
  int row = blockIdx.x;
  int tid = threadIdx.x;
  int t = row % TN;
  float* xr = X + (size_t)row*IN_DIM + KK;
  float c0 = fixnan(tracks[2*row]), c1 = fixnan(tracks[2*row+1]);
  float c2 = (float)t / (float)(TN - 1);
  if (tid == 0){ xr[0] = c0; xr[1] = c1; xr[2] = c2; }
  if (tid < 96){
    int coord = tid / 32;
    int r = tid % 32;
    float cv = (coord == 0) ? c0 : ((coord == 1) ? c1 : c2);
    int band = r & 15;
    float freq = exp2f(0.6f * (float)band) * 3.14159265358979323846f;
    float a = cv * freq;
    float v = (r < 16) ? sinf(a) : cosf(a);
    xr[3 + coord*32 + r] = fixnan(v);
  }
  X[(size_t)row*IN_DIM + (KK + 99) + tid] = fixnan(hd[(size_t)row*DN + tid]);
}

// ---- projection: row-GEMV 276 -> 128 ----
template<int MODE>
__global__ __launch_bounds__(128) void k_proj(const int* __restrict__ mf,
                                              const float* __restrict__ X,
                                              const void* __restrict__ pw,
                                              const void* __restrict__ pb,
                                              float* __restrict__ hd){
  if (mf[0] != MODE) return;
  int row = blockIdx.x;
  int n = threadIdx.x;
  __shared__ float xs[IN_DIM];
  for (int k = n; k < IN_DIM; k += 128) xs[k] = X[(size_t)row*IN_DIM + k];
  __syncthreads();
  float acc = ld<MODE>(pb, n);
  #pragma unroll 4
  for (int k = 0; k < IN_DIM; ++k)
    acc += xs[k] * ld<MODE>(pw, (size_t)k*DN + n);
  hd[(size_t)row*DN + n] = fixnan(acc);
}

// ---- LN1 + depthwise conv (T, k=5, pad=2) + residual; block per q ----
template<int MODE>
__global__ __launch_bounds__(256) void k_ln_conv(const int* __restrict__ mf,
                                                 float* __restrict__ hd,
                                                 const void* __restrict__ g,
                                                 const void* __restrict__ b,
                                                 const void* __restrict__ cw,
                                                 const void* __restrict__ cb,
                                                 int layer){
  if (mf[0] != MODE) return;
  int q = blockIdx.x;
  int tid = threadIdx.x;
  int wave = tid >> 6, lane = tid & 63;
  __shared__ float hn[TN][DN];
  for (int t = wave; t < TN; t += 4){
    int row = q*TN + t;
    float a0 = hd[(size_t)row*DN + lane];
    float a1 = hd[(size_t)row*DN + lane + 64];
    float m = waveReduceSum(a0 + a1) * (1.f/128.f);
    float v0 = a0 - m, v1 = a1 - m;
    float var = waveReduceSum(v0*v0 + v1*v1) * (1.f/128.f);
    float inv = rsqrtf(var + 1e-5f);
    hn[t][lane]      = v0*inv*ld<MODE>(g, layer*DN + lane)      + ld<MODE>(b, layer*DN + lane);
    hn[t][lane + 64] = v1*inv*ld<MODE>(g, layer*DN + lane + 64) + ld<MODE>(b, layer*DN + lane + 64);
  }
  __syncthreads();
  for (int idx = tid; idx < TN*DN; idx += 256){
    int t = idx / DN, d = idx % DN;
    float acc = ld<MODE>(cb, layer*DN + d);
    #pragma unroll
    for (int k = 0; k < 5; ++k){
      int tt = t + k - 2;
      if (tt >= 0 && tt < TN) acc += hn[tt][d] * ld<MODE>(cw, (size_t)layer*DN*5 + d*5 + k);
    }
    size_t o = (size_t)(q*TN + t)*DN + d;
    hd[o] = fixnan(hd[o] + acc);
  }
}

// ---- LN2 + MLP (128->256 gelu ->128) + residual; block per row ----
template<int MODE>
__global__ __launch_bounds__(128) void k_mlp(const int* __restrict__ mf,
                                             float* __restrict__ hd,
                                             const void* __restrict__ g,
                                             const void* __restrict__ b,
                                             const void* __restrict__ w1,
                                             const void* __restrict__ b1,
                                             const void* __restrict__ w2,
                                             const void* __restrict__ b2,
                                             int layer){
  if (mf[0] != MODE) return;
  int row = blockIdx.x;
  int tid = threadIdx.x;
  __shared__ float h2[DN];
  __shared__ float y1[2*DN];
  __shared__ float red[2];
  float v = hd[(size_t)row*DN + tid];
  float s = waveReduceSum(v);
  if ((tid & 63) == 0) red[tid >> 6] = s;
  __syncthreads();
  float m = (red[0] + red[1]) * (1.f/128.f);
  float dv = v - m;
  __syncthreads();
  float s2 = waveReduceSum(dv*dv);
  if ((tid & 63) == 0) red[tid >> 6] = s2;
  __syncthreads();
  float inv = rsqrtf((red[0] + red[1]) * (1.f/128.f) + 1e-5f);
  h2[tid] = dv*inv*ld<MODE>(g, layer*DN + tid) + ld<MODE>(b, layer*DN + tid);
  __syncthreads();

  const size_t w1o = (size_t)layer*DN*2*DN;
  float a0 = ld<MODE>(b1, layer*2*DN + tid);
  float a1 = ld<MODE>(b1, layer*2*DN + tid + 128);
  for (int k = 0; k < DN; ++k){
    float h = h2[k];
    a0 += h * ld<MODE>(w1, w1o + (size_t)k*256 + tid);
    a1 += h * ld<MODE>(w1, w1o + (size_t)k*256 + tid + 128);
  }
  y1[tid]       = gelu_exact(a0);
  y1[tid + 128] = gelu_exact(a1);
  __syncthreads();

  const size_t w2o = (size_t)layer*2*DN*DN;
  float acc = ld<MODE>(b2, layer*DN + tid);
  for (int j = 0; j < 2*DN; ++j)
    acc += y1[j] * ld<MODE>(w2, w2o + (size_t)j*DN + tid);
  hd[(size_t)row*DN + tid] = fixnan(v + acc);
}

// ---- heads: delta (128->2), vis (128->64 gelu ->1); update state ----
template<int MODE>
__global__ __launch_bounds__(64) void k_head(const int* __restrict__ mf,
                                             const float* __restrict__ hd,
                                             const void* __restrict__ dw,
                                             const void* __restrict__ db,
                                             const void* __restrict__ vw1,
                                             const void* __restrict__ vb1,
                                             const void* __restrict__ vw2,
                                             const void* __restrict__ vb2,
                                             float* __restrict__ tracks,
                                             float* __restrict__ vis_sum,
                                             void* __restrict__ out,
                                             int last){
  if (mf[0] != MODE) return;
  int row = blockIdx.x;
  int lane = threadIdx.x;
  __shared__ float xs[DN];
  float x0 = hd[(size_t)row*DN + lane];
  float x1 = hd[(size_t)row*DN + lane + 64];
  xs[lane] = x0; xs[lane + 64] = x1;
  __syncthreads();

  float a = ld<MODE>(vb1, lane);
  for (int k = 0; k < DN; ++k) a += xs[k] * ld<MODE>(vw1, (size_t)k*64 + lane);
  a = gelu_exact(a);
  float vis = waveReduceSum(a * ld<MODE>(vw2, lane));

  float dxp = x0*ld<MODE>(dw, lane*2 + 0) + x1*ld<MODE>(dw, (lane + 64)*2 + 0);
  float dyp = x0*ld<MODE>(dw, lane*2 + 1) + x1*ld<MODE>(dw, (lane + 64)*2 + 1);
  float dX = waveReduceSum(dxp);
  float dY = waveReduceSum(dyp);

  if (lane == 0){
    float tx = fixnan(tracks[2*row]   + dX + ld<MODE>(db, 0));
    float ty = fixnan(tracks[2*row+1] + dY + ld<MODE>(db, 1));
    tracks[2*row] = tx; tracks[2*row+1] = ty;
    float vs = fixnan(vis_sum[row] + vis + ld<MODE>(vb2, 0));
    vis_sum[row] = vs;
    if (last){
      if constexpr (MODE == 0){
        ((float*)out)[row*3 + 0] = tx;
        ((float*)out)[row*3 + 1] = ty;
        ((float*)out)[row*3 + 2] = vs * 0.25f;
      } else {
        ((bf16*)out)[row*3 + 0] = __float2bfloat16(tx);
        ((bf16*)out)[row*3 + 1] = __float2bfloat16(ty);
        ((bf16*)out)[row*3 + 2] = __float2bfloat16(vs * 0.25f);
      }
    }
  }
}

template<int MODE>
static void run_pipeline(const int* mf, void* const* d_in, void* d_out,
                         float* tracks, float* vis_sum, float* X, float* hd,
                         hipStream_t stream){
  const void* ct    = d_in[0];
  const void* query = d_in[1];
  const void* fmap  = d_in[2];
  const void* fs    = d_in[3];
  const void* pw    = d_in[4];
  const void* pb    = d_in[5];
  const void* ln1g  = d_in[6];
  const void* ln1b  = d_in[7];
  const void* cw    = d_in[8];
  const void* cb    = d_in[9];
  const void* ln2g  = d_in[10];
  const void* ln2b  = d_in[11];
  const void* w1    = d_in[12];
  const void* b1    = d_in[13];
  const void* w2    = d_in[14];
  const void* b2    = d_in[15];
  const void* dw    = d_in[16];
  const void* db    = d_in[17];
  const void* vw1   = d_in[18];
  const void* vb1   = d_in[19];
  const void* vw2   = d_in[20];
  const void* vb2   = d_in[21];

  k_init<MODE><<<(NROWS + 255)/256, 256, 0, stream>>>(mf, ct, tracks, vis_sum);
  for (int it = 0; it < 4; ++it){
    k_corr<MODE><<<NROWS, 64, 0, stream>>>(mf, fmap, query, tracks, fs, X);
    k_assemble<MODE><<<NROWS, 128, 0, stream>>>(mf, tracks, hd, X);
    k_proj<MODE><<<NROWS, 128, 0, stream>>>(mf, X, pw, pb, hd);
    for (int l = 0; l < 4; ++l){
      k_ln_conv<MODE><<<QN, 256, 0, stream>>>(mf, hd, ln1g, ln1b, cw, cb, l);
      k_mlp<MODE><<<NROWS, 128, 0, stream>>>(mf, hd, ln2g, ln2b, w1, b1, w2, b2, l);
    }
    k_head<MODE><<<NROWS, 64, 0, stream>>>(mf, hd, dw, db, vw1, vb1, vw2, vb2,
                                           tracks, vis_sum, d_out, it == 3);
  }
}

extern "C" void kernel_launch(void* const* d_in, const int* in_sizes, int n_in,
                              void* d_out, int out_size, void* d_ws, size_t ws_size,
                              hipStream_t stream) {
  char* w = (char*)d_ws;
  int*   mflag   = (int*)w;                 w += 256;
  float* tracks  = (float*)w;               w += ((size_t)NROWS*2*4 + 255) & ~255ull;
  float* vis_sum = (float*)w;               w += ((size_t)NROWS*4   + 255) & ~255ull;
  float* X       = (float*)w;               w += ((size_t)NROWS*IN_DIM*4 + 255) & ~255ull;
  float* hd      = (float*)w;               w += ((size_t)NROWS*DN*4 + 255) & ~255ull;

  k_sniff<<<1, 256, 0, stream>>>((const unsigned short*)d_in[1], mflag);
  hipMemsetAsync(hd, 0, (size_t)NROWS*DN*4, stream);

  run_pipeline<0>(mflag, d_in, d_out, tracks, vis_sum, X, hd, stream);
  run_pipeline<1>(mflag, d_in, d_out, tracks, vis_sum, X, hd, stream);
}

// Round 3
// 1337.055 us; speedup vs baseline: 1.2680x; 1.2680x over previous
//
#include <hip/hip_runtime.h>
#include <hip/hip_bf16.h>
#include <math.h>

#define QN 128
#define TN 48
#define CN 64
#define HN 96
#define WN 128
#define DN 128
#define KK 49
#define IN_DIM 276
#define XPAD 288
#define NROWS (QN*TN)

typedef __hip_bfloat16 bf16;
using bf16x8 = __attribute__((ext_vector_type(8))) short;
using f32x4  = __attribute__((ext_vector_type(4))) float;

__device__ inline float fixnan(float x){ return (x == x && fabsf(x) < 1e30f) ? x : 0.f; }

// MODE 0: buffers are float32. MODE 1: buffers are bf16.
template<int MODE> __device__ inline float ld(const void* p, size_t i){
  if constexpr (MODE == 0) return ((const float*)p)[i];
  else {
    unsigned int u = ((const unsigned short*)p)[i];
    return __uint_as_float(u << 16);
  }
}

__device__ inline short f2b(float x){
  __hip_bfloat16 h = __float2bfloat16(x);
  return *reinterpret_cast<short*>(&h);
}

__device__ inline float waveReduceSum(float v){
  #pragma unroll
  for (int off = 32; off > 0; off >>= 1) v += __shfl_xor(v, off, 64);
  return v;
}

__device__ inline float gelu_exact(float x){
  return 0.5f * x * (1.f + erff(x * 0.70710678118654752440f));
}

__device__ inline f32x4 mfma16(bf16x8 a, bf16x8 b, f32x4 c){
  return __builtin_amdgcn_mfma_f32_16x16x32_bf16(a, b, c, 0, 0, 0);
}

__device__ inline float decode_stride(const void* p){
  int iv = *(const int*)p;
  if (iv >= 1 && iv <= (1 << 20)) return (float)iv;
  float fv = __int_as_float(iv);
  if (fv == fv && fv >= 0.25f && fv <= 1048576.f) return fv;
  unsigned int lo = ((unsigned int)(*(const unsigned short*)p)) << 16;
  float bv = __uint_as_float(lo);
  if (bv == bv && bv >= 0.25f && bv <= 1048576.f) return bv;
  return 4.f;
}

// ---- dtype sniffer on query_features ----
__global__ __launch_bounds__(256) void k_sniff(const unsigned short* __restrict__ q,
                                               int* __restrict__ flag){
  __shared__ int cnt;
  if (threadIdx.x == 0) cnt = 0;
  __syncthreads();
  int good = 0;
  for (int i = threadIdx.x; i < 8192; i += 256){
    float v = __uint_as_float(((unsigned int)q[i]) << 16);
    float a = fabsf(v);
    if (a > 1e-3f && a < 30.f) good++;
  }
  atomicAdd(&cnt, good);
  __syncthreads();
  if (threadIdx.x == 0) flag[0] = (cnt > 6500) ? 1 : 0;  // 1 = bf16 data
}

// ---- weight transposes (bf16, once per launch) ----
template<int MODE>
__device__ void transW_impl(int idx, const void* pw, const void* w1, const void* w2,
                            bf16* pwt, bf16* w1t, bf16* w2t){
  if (idx < 128*XPAD){
    int n = idx / XPAD, kk = idx % XPAD;
    float v = (kk < IN_DIM) ? ld<MODE>(pw, (size_t)kk*DN + n) : 0.f;
    ((short*)pwt)[idx] = f2b(v);
  } else if (idx < 128*XPAD + 4*256*128){
    int i2 = idx - 128*XPAD;
    int k = i2 & 127, n = (i2 >> 7) & 255, l = i2 >> 15;
    ((short*)w1t)[i2] = f2b(ld<MODE>(w1, (size_t)l*32768 + (size_t)k*256 + n));
  } else {
    int i3 = idx - 128*XPAD - 4*256*128;
    int k = i3 & 255, n = (i3 >> 8) & 127, l = i3 >> 15;
    ((short*)w2t)[i3] = f2b(ld<MODE>(w2, (size_t)l*32768 + (size_t)k*128 + n));
  }
}
__global__ __launch_bounds__(256) void k_transW(const int* __restrict__ mf,
    const void* pw, const void* w1, const void* w2,
    bf16* pwt, bf16* w1t, bf16* w2t){
  int idx = blockIdx.x*256 + threadIdx.x;
  int total = 128*XPAD + 4*256*128 + 4*128*256;
  if (idx >= total) return;
  if (mf[0] == 0) transW_impl<0>(idx, pw, w1, w2, pwt, w1t, w2t);
  else            transW_impl<1>(idx, pw, w1, w2, pwt, w1t, w2t);
}

// ---- init ----
template<int MODE>
__device__ void init_impl(const void* ct, float* tracks, float* vis_sum){
  int i = blockIdx.x * 256 + threadIdx.x;
  if (i < NROWS){
    tracks[2*i]   = fixnan(ld<MODE>(ct, 2*i));
    tracks[2*i+1] = fixnan(ld<MODE>(ct, 2*i+1));
    vis_sum[i] = 0.f;
  }
}
__global__ __launch_bounds__(256) void k_init(const int* __restrict__ mf,
    const void* ct, float* tracks, float* vis_sum){
  if (mf[0] == 0) init_impl<0>(ct, tracks, vis_sum);
  else            init_impl<1>(ct, tracks, vis_sum);
}

// ---- local correlation: one wave per (q,t); writes bf16 X cols 0..48 ----
template<int MODE>
__device__ void corr_impl(float* qv, float (*dots)[8],
                          const void* fmap, const void* query,
                          const float* tracks, const void* stride_p, short* Xb){
  int blk = blockIdx.x;
  int q = blk / TN, t = blk % TN;
  int lane = threadIdx.x;
  qv[lane] = ld<MODE>(query, q*CN + lane);
  __syncthreads();

  float fs = decode_stride(stride_p);
  float px = fixnan(tracks[2*blk]   / fs);
  float py = fixnan(tracks[2*blk+1] / fs);
  px = fminf(fmaxf(px, -1e6f), 1e6f);
  py = fminf(fmaxf(py, -1e6f), 1e6f);
  float fx0 = floorf(px), fy0 = floorf(py);
  float dx = px - fx0, dy = py - fy0;
  int bx = (int)fx0, by = (int)fy0;

  int j = lane >> 3, i = lane & 7;
  int xi = bx + i - 3, yi = by + j - 3;
  float dot = 0.f;
  if (xi >= 0 && xi < WN && yi >= 0 && yi < HN){
    size_t base = (size_t)t*CN*HN*WN + (size_t)yi*WN + xi;
    #pragma unroll 8
    for (int c = 0; c < CN; ++c)
      dot += qv[c] * ld<MODE>(fmap, base + (size_t)c*HN*WN);
  }
  dots[j][i] = dot;
  __syncthreads();

  if (lane < KK){
    int oy = lane / 7, ox = lane % 7;
    float w00 = (1.f-dx)*(1.f-dy), w01 = dx*(1.f-dy);
    float w10 = (1.f-dx)*dy,       w11 = dx*dy;
    float v = w00*dots[oy][ox]   + w01*dots[oy][ox+1]
            + w10*dots[oy+1][ox] + w11*dots[oy+1][ox+1];
    Xb[(size_t)blk*XPAD + lane] = f2b(fixnan(v));
  }
}
__global__ __launch_bounds__(64) void k_corr(const int* __restrict__ mf,
    const void* fmap, const void* query, const float* tracks,
    const void* stride_p, short* Xb){
  __shared__ float qv[CN];
  __shared__ float dots[8][8];
  if (mf[0] == 0) corr_impl<0>(qv, dots, fmap, query, tracks, stride_p, Xb);
  else            corr_impl<1>(qv, dots, fmap, query, tracks, stride_p, Xb);
}

// ---- fourier pos-enc + hidden copy into bf16 X ----
__global__ __launch_bounds__(128) void k_assemble(const float* __restrict__ tracks,
                                                  const float* __restrict__ hd,
                                                  short* __restrict__ Xb){
  int row = blockIdx.x;
  int tid = threadIdx.x;
  int t = row % TN;
  short* xr = Xb + (size_t)row*XPAD + KK;
  float c0 = fixnan(tracks[2*row]), c1 = fixnan(tracks[2*row+1]);
  float c2 = (float)t / (float)(TN - 1);
  if (tid == 0){ xr[0] = f2b(c0); xr[1] = f2b(c1); xr[2] = f2b(c2); }
  if (tid < 96){
    int coord = tid / 32;
    int r = tid % 32;
    float cv = (coord == 0) ? c0 : ((coord == 1) ? c1 : c2);
    int band = r & 15;
    float freq = exp2f(0.6f * (float)band) * 3.14159265358979323846f;
    float a = cv * freq;
    float v = (r < 16) ? sinf(a) : cosf(a);
    xr[3 + coord*32 + r] = f2b(fixnan(v));
  }
  if (tid >= 96 && tid < 108) Xb[(size_t)row*XPAD + IN_DIM + (tid - 96)] = 0;
  Xb[(size_t)row*XPAD + (KK + 99) + tid] = f2b(fixnan(hd[(size_t)row*DN + tid]));
}

// ---- proj: MFMA GEMM X[6144x288]@pwt^T -> hd ; 16 rows/wave, 64 rows/block ----
template<int MODE>
__device__ void proj_impl(const short* Xb, const bf16* pwt, const void* pb, float* hd){
  int tid = threadIdx.x;
  int wv = tid >> 6, l = tid & 63;
  int row0 = blockIdx.x*64 + wv*16;
  int rA = l & 15, gK = l >> 4;

  f32x4 acc[8];
  #pragma unroll
  for (int nt = 0; nt < 8; ++nt){
    float b = ld<MODE>(pb, nt*16 + rA);
    acc[nt] = {b, b, b, b};
  }
  const short* pwts = (const short*)pwt;
  #pragma unroll
  for (int ks = 0; ks < 9; ++ks){
    int k0 = ks*32 + gK*8;
    bf16x8 af = *(const bf16x8*)(Xb + (size_t)(row0 + rA)*XPAD + k0);
    #pragma unroll
    for (int nt = 0; nt < 8; ++nt){
      bf16x8 bfv = *(const bf16x8*)(pwts + (size_t)(nt*16 + rA)*XPAD + k0);
      acc[nt] = mfma16(af, bfv, acc[nt]);
    }
  }
  #pragma unroll
  for (int nt = 0; nt < 8; ++nt){
    #pragma unroll
    for (int rr = 0; rr < 4; ++rr){
      int row = row0 + (l >> 4)*4 + rr;
      int col = nt*16 + (l & 15);
      hd[(size_t)row*DN + col] = acc[nt][rr];
    }
  }
}
__global__ __launch_bounds__(256) void k_proj(const int* __restrict__ mf,
    const short* Xb, const bf16* pwt, const void* pb, float* hd){
  if (mf[0] == 0) proj_impl<0>(Xb, pwt, pb, hd);
  else            proj_impl<1>(Xb, pwt, pb, hd);
}

// ---- LN1 + depthwise conv + residual; block per q ----
template<int MODE>
__device__ void lnconv_impl(float (*hn)[DN], float* hd, const void* g, const void* b,
                            const void* cw, const void* cb, int layer){
  int q = blockIdx.x;
  int tid = threadIdx.x;
  int wave = tid >> 6, lane = tid & 63;
  for (int t = wave; t < TN; t += 4){
    int row = q*TN + t;
    float a0 = hd[(size_t)row*DN + lane];
    float a1 = hd[(size_t)row*DN + lane + 64];
    float m = waveReduceSum(a0 + a1) * (1.f/128.f);
    float v0 = a0 - m, v1 = a1 - m;
    float var = waveReduceSum(v0*v0 + v1*v1) * (1.f/128.f);
    float inv = rsqrtf(var + 1e-5f);
    hn[t][lane]      = v0*inv*ld<MODE>(g, layer*DN + lane)      + ld<MODE>(b, layer*DN + lane);
    hn[t][lane + 64] = v1*inv*ld<MODE>(g, layer*DN + lane + 64) + ld<MODE>(b, layer*DN + lane + 64);
  }
  __syncthreads();
  for (int idx = tid; idx < TN*DN; idx += 256){
    int t = idx / DN, d = idx % DN;
    float acc = ld<MODE>(cb, layer*DN + d);
    #pragma unroll
    for (int k = 0; k < 5; ++k){
      int tt = t + k - 2;
      if (tt >= 0 && tt < TN) acc += hn[tt][d] * ld<MODE>(cw, (size_t)layer*DN*5 + d*5 + k);
    }
    size_t o = (size_t)(q*TN + t)*DN + d;
    hd[o] = fixnan(hd[o] + acc);
  }
}
__global__ __launch_bounds__(256) void k_lnconv(const int* __restrict__ mf,
    float* hd, const void* g, const void* b, const void* cw, const void* cb, int layer){
  __shared__ float hn[TN][DN];
  if (mf[0] == 0) lnconv_impl<0>(hn, hd, g, b, cw, cb, layer);
  else            lnconv_impl<1>(hn, hd, g, b, cw, cb, layer);
}

// ---- LN2 + MLP via MFMA + residual; 16 rows/wave, 64 rows/block, grid 96 ----
template<int MODE>
__device__ void layer_impl(char* lds, float* hd, const void* g, const void* b,
                           const bf16* w1t, const void* b1,
                           const bf16* w2t, const void* b2, int layer){
  int tid = threadIdx.x;
  int wv = tid >> 6, l = tid & 63;
  char* h2s = lds + wv*(16*256 + 16*512);
  char* y1s = h2s + 16*256;
  int row0 = blockIdx.x*64 + wv*16;
  int rA = l & 15, gK = l >> 4;

  float g0 = ld<MODE>(g, layer*DN + l), g1 = ld<MODE>(g, layer*DN + l + 64);
  float c0 = ld<MODE>(b, layer*DN + l), c1 = ld<MODE>(b, layer*DN + l + 64);
  for (int r = 0; r < 16; ++r){
    const float* hp = hd + (size_t)(row0 + r)*DN;
    float a0 = hp[l], a1 = hp[l + 64];
    float m = waveReduceSum(a0 + a1) * (1.f/128.f);
    float v0 = a0 - m, v1 = a1 - m;
    float var = waveReduceSum(v0*v0 + v1*v1) * (1.f/128.f);
    float inv = rsqrtf(var + 1e-5f);
    int sw = (r & 7) << 4;
    *(short*)(h2s + r*256 + ((l*2) ^ sw))        = f2b(v0*inv*g0 + c0);
    *(short*)(h2s + r*256 + (((l + 64)*2) ^ sw)) = f2b(v1*inv*g1 + c1);
  }
  __syncthreads();

  // GEMM1: h2[16x128] @ w1[128x256]
  f32x4 acc[16];
  #pragma unroll
  for (int nt = 0; nt < 16; ++nt){
    float bv = ld<MODE>(b1, layer*256 + nt*16 + rA);
    acc[nt] = {bv, bv, bv, bv};
  }
  const short* w1s = (const short*)w1t + (size_t)layer*256*128;
  #pragma unroll
  for (int ks = 0; ks < 4; ++ks){
    int k0 = ks*32 + gK*8;
    bf16x8 af = *(const bf16x8*)(h2s + rA*256 + ((k0*2) ^ ((rA & 7) << 4)));
    #pragma unroll
    for (int nt = 0; nt < 16; ++nt){
      bf16x8 bfv = *(const bf16x8*)(w1s + (size_t)(nt*16 + rA)*128 + k0);
      acc[nt] = mfma16(af, bfv, acc[nt]);
    }
  }
  // GELU -> y1s (bf16, swizzled)
  #pragma unroll
  for (int nt = 0; nt < 16; ++nt){
    #pragma unroll
    for (int rr = 0; rr < 4; ++rr){
      int row = (l >> 4)*4 + rr;
      int col = nt*16 + (l & 15);
      *(short*)(y1s + row*512 + ((col*2) ^ ((row & 7) << 4))) = f2b(gelu_exact(acc[nt][rr]));
    }
  }
  __syncthreads();

  // GEMM2: y1[16x256] @ w2[256x128]
  f32x4 acc2[8];
  #pragma unroll
  for (int nt = 0; nt < 8; ++nt){
    float bv = ld<MODE>(b2, layer*DN + nt*16 + rA);
    acc2[nt] = {bv, bv, bv, bv};
  }
  const short* w2s = (const short*)w2t + (size_t)layer*128*256;
  #pragma unroll
  for (int ks = 0; ks < 8; ++ks){
    int k0 = ks*32 + gK*8;
    bf16x8 af = *(const bf16x8*)(y1s + rA*512 + ((k0*2) ^ ((rA & 7) << 4)));
    #pragma unroll
    for (int nt = 0; nt < 8; ++nt){
      bf16x8 bfv = *(const bf16x8*)(w2s + (size_t)(nt*16 + rA)*256 + k0);
      acc2[nt] = mfma16(af, bfv, acc2[nt]);
    }
  }
  // residual
  #pragma unroll
  for (int nt = 0; nt < 8; ++nt){
    #pragma unroll
    for (int rr = 0; rr < 4; ++rr){
      int row = row0 + (l >> 4)*4 + rr;
      int col = nt*16 + (l & 15);
      size_t o = (size_t)row*DN + col;
      hd[o] = fixnan(hd[o] + acc2[nt][rr]);
    }
  }
}
__global__ __launch_bounds__(256) void k_layer(const int* __restrict__ mf,
    float* hd, const void* g, const void* b, const bf16* w1t, const void* b1,
    const bf16* w2t, const void* b2, int layer){
  __shared__ char lds[4*(16*256 + 16*512)];
  if (mf[0] == 0) layer_impl<0>(lds, hd, g, b, w1t, b1, w2t, b2, layer);
  else            layer_impl<1>(lds, hd, g, b, w1t, b1, w2t, b2, layer);
}

// ---- heads ----
template<int MODE>
__device__ void head_impl(float* xs, const float* hd, const void* dw, const void* db,
                          const void* vw1, const void* vb1, const void* vw2, const void* vb2,
                          float* tracks, float* vis_sum, void* out, int last){
  int row = blockIdx.x;
  int lane = threadIdx.x;
  float x0 = hd[(size_t)row*DN + lane];
  float x1 = hd[(size_t)row*DN + lane + 64];
  xs[lane] = x0; xs[lane + 64] = x1;
  __syncthreads();

  float a = ld<MODE>(vb1, lane);
  for (int k = 0; k < DN; ++k) a += xs[k] * ld<MODE>(vw1, (size_t)k*64 + lane);
  a = gelu_exact(a);
  float vis = waveReduceSum(a * ld<MODE>(vw2, lane));

  float dxp = x0*ld<MODE>(dw, lane*2 + 0) + x1*ld<MODE>(dw, (lane + 64)*2 + 0);
  float dyp = x0*ld<MODE>(dw, lane*2 + 1) + x1*ld<MODE>(dw, (lane + 64)*2 + 1);
  float dX = waveReduceSum(dxp);
  float dY = waveReduceSum(dyp);

  if (lane == 0){
    float tx = fixnan(tracks[2*row]   + dX + ld<MODE>(db, 0));
    float ty = fixnan(tracks[2*row+1] + dY + ld<MODE>(db, 1));
    tracks[2*row] = tx; tracks[2*row+1] = ty;
    float vs = fixnan(vis_sum[row] + vis + ld<MODE>(vb2, 0));
    vis_sum[row] = vs;
    if (last){
      if constexpr (MODE == 0){
        ((float*)out)[row*3 + 0] = tx;
        ((float*)out)[row*3 + 1] = ty;
        ((float*)out)[row*3 + 2] = vs * 0.25f;
      } else {
        ((bf16*)out)[row*3 + 0] = __float2bfloat16(tx);
        ((bf16*)out)[row*3 + 1] = __float2bfloat16(ty);
        ((bf16*)out)[row*3 + 2] = __float2bfloat16(vs * 0.25f);
      }
    }
  }
}
__global__ __launch_bounds__(64) void k_head(const int* __restrict__ mf,
    const float* hd, const void* dw, const void* db,
    const void* vw1, const void* vb1, const void* vw2, const void* vb2,
    float* tracks, float* vis_sum, void* out, int last){
  __shared__ float xs[DN];
  if (mf[0] == 0) head_impl<0>(xs, hd, dw, db, vw1, vb1, vw2, vb2, tracks, vis_sum, out, last);
  else            head_impl<1>(xs, hd, dw, db, vw1, vb1, vw2, vb2, tracks, vis_sum, out, last);
}

extern "C" void kernel_launch(void* const* d_in, const int* in_sizes, int n_in,
                              void* d_out, int out_size, void* d_ws, size_t ws_size,
                              hipStream_t stream) {
  const void* ct    = d_in[0];
  const void* query = d_in[1];
  const void* fmap  = d_in[2];
  const void* fs    = d_in[3];
  const void* pw    = d_in[4];
  const void* pb    = d_in[5];
  const void* ln1g  = d_in[6];
  const void* ln1b  = d_in[7];
  const void* cw    = d_in[8];
  const void* cb    = d_in[9];
  const void* ln2g  = d_in[10];
  const void* ln2b  = d_in[11];
  const void* w1    = d_in[12];
  const void* b1    = d_in[13];
  const void* w2    = d_in[14];
  const void* b2    = d_in[15];
  const void* dw    = d_in[16];
  const void* db    = d_in[17];
  const void* vw1   = d_in[18];
  const void* vb1   = d_in[19];
  const void* vw2   = d_in[20];
  const void* vb2   = d_in[21];

  char* w = (char*)d_ws;
  int*   mflag   = (int*)w;                 w += 256;
  float* tracks  = (float*)w;               w += ((size_t)NROWS*2*4 + 255) & ~255ull;
  float* vis_sum = (float*)w;               w += ((size_t)NROWS*4   + 255) & ~255ull;
  short* Xb      = (short*)w;               w += ((size_t)NROWS*XPAD*2 + 255) & ~255ull;
  float* hd      = (float*)w;               w += ((size_t)NROWS*DN*4 + 255) & ~255ull;
  bf16*  pwt     = (bf16*)w;                w += ((size_t)128*XPAD*2 + 255) & ~255ull;
  bf16*  w1t     = (bf16*)w;                w += ((size_t)4*256*128*2 + 255) & ~255ull;
  bf16*  w2t     = (bf16*)w;                w += ((size_t)4*128*256*2 + 255) & ~255ull;

  k_sniff<<<1, 256, 0, stream>>>((const unsigned short*)query, mflag);
  hipMemsetAsync(hd, 0, (size_t)NROWS*DN*4, stream);

  int totT = 128*XPAD + 4*256*128 + 4*128*256;
  k_transW<<<(totT + 255)/256, 256, 0, stream>>>(mflag, pw, w1, w2, pwt, w1t, w2t);
  k_init<<<(NROWS + 255)/256, 256, 0, stream>>>(mflag, ct, tracks, vis_sum);

  for (int it = 0; it < 4; ++it){
    k_corr<<<NROWS, 64, 0, stream>>>(mflag, fmap, query, tracks, fs, Xb);
    k_assemble<<<NROWS, 128, 0, stream>>>(tracks, hd, Xb);
    k_proj<<<NROWS/64, 256, 0, stream>>>(mflag, Xb, pwt, pb, hd);
    for (int l = 0; l < 4; ++l){
      k_lnconv<<<QN, 256, 0, stream>>>(mflag, hd, ln1g, ln1b, cw, cb, l);
      k_layer<<<NROWS/64, 256, 0, stream>>>(mflag, hd, ln2g, ln2b, w1t, b1, w2t, b2, l);
    }
    k_head<<<NROWS, 64, 0, stream>>>(mflag, hd, dw, db, vw1, vb1, vw2, vb2,
                                     tracks, vis_sum, d_out, it == 3);
  }
}

// Round 4
// 574.746 us; speedup vs baseline: 2.9498x; 2.3263x over previous
//
#include <hip/hip_runtime.h>
#include <hip/hip_bf16.h>
#include <math.h>

#define QN 128
#define TN 48
#define CN 64
#define HN 96
#define WN 128
#define DN 128
#define KK 49
#define IN_DIM 276
#define XPAD 288
#define NROWS (QN*TN)
#define PI_F 3.14159265358979323846f

typedef __hip_bfloat16 bf16;
using bf16x8 = __attribute__((ext_vector_type(8))) short;
using f32x4  = __attribute__((ext_vector_type(4))) float;

__device__ inline float fixnan(float x){ return (x == x && fabsf(x) < 1e30f) ? x : 0.f; }

// MODE 0: buffers are float32. MODE 1: buffers are bf16.
template<int MODE> __device__ inline float ld(const void* p, size_t i){
  if constexpr (MODE == 0) return ((const float*)p)[i];
  else {
    unsigned int u = ((const unsigned short*)p)[i];
    return __uint_as_float(u << 16);
  }
}

__device__ inline short f2b(float x){
  __hip_bfloat16 h = __float2bfloat16(x);
  return *reinterpret_cast<short*>(&h);
}

__device__ inline float waveReduceSum(float v){
  #pragma unroll
  for (int off = 32; off > 0; off >>= 1) v += __shfl_xor(v, off, 64);
  return v;
}

__device__ inline float gelu_exact(float x){
  return 0.5f * x * (1.f + erff(x * 0.70710678118654752440f));
}

__device__ inline f32x4 mfma16(bf16x8 a, bf16x8 b, f32x4 c){
  return __builtin_amdgcn_mfma_f32_16x16x32_bf16(a, b, c, 0, 0, 0);
}

__device__ inline float decode_stride(const void* p){
  int iv = *(const int*)p;
  if (iv >= 1 && iv <= (1 << 20)) return (float)iv;
  float fv = __int_as_float(iv);
  if (fv == fv && fv >= 0.25f && fv <= 1048576.f) return fv;
  unsigned int lo = ((unsigned int)(*(const unsigned short*)p)) << 16;
  float bv = __uint_as_float(lo);
  if (bv == bv && bv >= 0.25f && bv <= 1048576.f) return bv;
  return 4.f;
}

// swizzled bf16 LDS tile accessors (stride_sh = shorts per row; row stride must be mult of 128B)
__device__ inline void bput(short* base, int stride_sh, int r, int k, float v){
  *(short*)((char*)base + (size_t)r*stride_sh*2 + ((2*k) ^ ((r & 7) << 4))) = f2b(v);
}
__device__ inline float bget(const short* base, int stride_sh, int r, int k){
  unsigned short u = *(const unsigned short*)((const char*)base + (size_t)r*stride_sh*2 + ((2*k) ^ ((r & 7) << 4)));
  return __uint_as_float(((unsigned int)u) << 16);
}
__device__ inline bf16x8 bget8(const short* base, int stride_sh, int r, int k0){
  return *(const bf16x8*)((const char*)base + (size_t)r*stride_sh*2 + ((2*k0) ^ ((r & 7) << 4)));
}

struct SLds {
  float qv[CN];
  float sdx[32], sdy[32], sc0[32], sc1[32];
  float hdl[32][132];                       // f32 working tile (padded stride)
  union {
    struct { float dots[32][64]; short Xs[32][320]; } a;   // corr + X stage (Xs row = 640B)
    struct { short hn[32][128]; short y1[32][256]; } b;    // normed + mlp-mid
  } u;
};

// ---- dtype sniffer ----
__global__ __launch_bounds__(256) void k_sniff(const unsigned short* __restrict__ q,
                                               int* __restrict__ flag){
  __shared__ int cnt;
  if (threadIdx.x == 0) cnt = 0;
  __syncthreads();
  int good = 0;
  for (int i = threadIdx.x; i < 8192; i += 256){
    float v = __uint_as_float(((unsigned int)q[i]) << 16);
    float a = fabsf(v);
    if (a > 1e-3f && a < 30.f) good++;
  }
  atomicAdd(&cnt, good);
  __syncthreads();
  if (threadIdx.x == 0) flag[0] = (cnt > 6500) ? 1 : 0;
}

// ---- weight transposes ----
template<int MODE>
__device__ void transW_impl(int idx, const void* pw, const void* w1, const void* w2,
                            bf16* pwt, bf16* w1t, bf16* w2t){
  if (idx < 128*XPAD){
    int n = idx / XPAD, kk = idx % XPAD;
    float v = (kk < IN_DIM) ? ld<MODE>(pw, (size_t)kk*DN + n) : 0.f;
    ((short*)pwt)[idx] = f2b(v);
  } else if (idx < 128*XPAD + 4*256*128){
    int i2 = idx - 128*XPAD;
    int k = i2 & 127, n = (i2 >> 7) & 255, l = i2 >> 15;
    ((short*)w1t)[i2] = f2b(ld<MODE>(w1, (size_t)l*32768 + (size_t)k*256 + n));
  } else {
    int i3 = idx - 128*XPAD - 4*256*128;
    int k = i3 & 255, n = (i3 >> 8) & 127, l = i3 >> 15;
    ((short*)w2t)[i3] = f2b(ld<MODE>(w2, (size_t)l*32768 + (size_t)k*128 + n));
  }
}
__global__ __launch_bounds__(256) void k_transW(const int* __restrict__ mf,
    const void* pw, const void* w1, const void* w2,
    bf16* pwt, bf16* w1t, bf16* w2t){
  int idx = blockIdx.x*256 + threadIdx.x;
  int total = 128*XPAD + 4*256*128 + 4*128*256;
  if (idx >= total) return;
  if (mf[0] == 0) transW_impl<0>(idx, pw, w1, w2, pwt, w1t, w2t);
  else            transW_impl<1>(idx, pw, w1, w2, pwt, w1t, w2t);
}

// ---- init ----
template<int MODE>
__device__ void init_impl(const void* ct, float* tracks, float* vis_sum){
  int i = blockIdx.x * 256 + threadIdx.x;
  if (i < NROWS){
    tracks[2*i]   = fixnan(ld<MODE>(ct, 2*i));
    tracks[2*i+1] = fixnan(ld<MODE>(ct, 2*i+1));
    vis_sum[i] = 0.f;
  }
}
__global__ __launch_bounds__(256) void k_init(const int* __restrict__ mf,
    const void* ct, float* tracks, float* vis_sum){
  if (mf[0] == 0) init_impl<0>(ct, tracks, vis_sum);
  else            init_impl<1>(ct, tracks, vis_sum);
}

// ==== fused per-iteration kernel: block = (q, t-half); 32 rows w/ 8-row halo ====
template<int MODE>
__device__ void iter_impl(SLds& s,
    const void* fmap, const void* query, const void* stride_p,
    const float* __restrict__ tr_in, float* __restrict__ tr_out,
    const float* __restrict__ vi_in, float* __restrict__ vi_out,
    const float* __restrict__ hd_in, float* __restrict__ hd_out,
    const bf16* pwt, const void* pb,
    const void* ln1g, const void* ln1b, const void* cw, const void* cb,
    const void* ln2g, const void* ln2b,
    const bf16* w1t, const void* b1, const bf16* w2t, const void* b2,
    const void* dwp, const void* dbp,
    const void* vw1, const void* vb1, const void* vw2, const void* vb2,
    void* out, int last)
{
  int bid = blockIdx.x;
  int q = bid >> 1, half = bid & 1, T0 = half * 16;
  int tid = threadIdx.x, wv = tid >> 6, ll = tid & 63;

  if (tid < CN) s.qv[tid] = ld<MODE>(query, q*CN + tid);
  float fs = decode_stride(stride_p);
  __syncthreads();

  // ---- Phase 1: corr dots (8x8 taps per row) ----
  for (int rr = 0; rr < 4; ++rr){
    int r = wv*4 + rr, t = T0 + r, grow = q*TN + t;
    float c0 = fixnan(tr_in[2*grow]), c1 = fixnan(tr_in[2*grow+1]);
    float px = fminf(fmaxf(c0 / fs, -1e6f), 1e6f);
    float py = fminf(fmaxf(c1 / fs, -1e6f), 1e6f);
    float fx0 = floorf(px), fy0 = floorf(py);
    if (ll == 0){ s.sdx[r] = px - fx0; s.sdy[r] = py - fy0; s.sc0[r] = c0; s.sc1[r] = c1; }
    int bx = (int)fx0, by = (int)fy0;
    int j = ll >> 3, i = ll & 7;
    int xi = bx + i - 3, yi = by + j - 3;
    float dot = 0.f;
    if (xi >= 0 && xi < WN && yi >= 0 && yi < HN){
      size_t base = ((size_t)t*CN)*HN*WN + (size_t)yi*WN + xi;
      #pragma unroll 8
      for (int c = 0; c < CN; ++c)
        dot += s.qv[c] * ld<MODE>(fmap, base + (size_t)c*HN*WN);
    }
    s.u.a.dots[r][ll] = dot;
  }
  __syncthreads();

  // ---- Phase 2: assemble X (bf16, swizzled) ----
  for (int idx = tid; idx < 32*KK; idx += 512){
    int r = idx / KK, kk = idx % KK, oy = kk / 7, ox = kk % 7;
    float dx = s.sdx[r], dy = s.sdy[r];
    const float* dr = s.u.a.dots[r];
    float v = (1.f-dx)*(1.f-dy)*dr[oy*8+ox]     + dx*(1.f-dy)*dr[oy*8+ox+1]
            + (1.f-dx)*dy*dr[(oy+1)*8+ox]       + dx*dy*dr[(oy+1)*8+ox+1];
    bput(&s.u.a.Xs[0][0], 320, r, kk, fixnan(v));
  }
  for (int idx = tid; idx < 32*3; idx += 512){
    int r = idx / 3, cd = idx % 3;
    float v = (cd == 0) ? s.sc0[r] : (cd == 1 ? s.sc1[r] : (float)(T0+r)/(float)(TN-1));
    bput(&s.u.a.Xs[0][0], 320, r, KK + cd, v);
  }
  for (int idx = tid; idx < 32*96; idx += 512){
    int r = idx / 96, j = idx % 96, coord = j >> 5, rm = j & 31, band = rm & 15;
    float cv = (coord == 0) ? s.sc0[r] : (coord == 1 ? s.sc1[r] : (float)(T0+r)/(float)(TN-1));
    float a = cv * exp2f(0.6f*(float)band) * PI_F;
    float v = (rm < 16) ? sinf(a) : cosf(a);
    bput(&s.u.a.Xs[0][0], 320, r, KK + 3 + coord*32 + rm, fixnan(v));
  }
  for (int idx = tid; idx < 32*DN; idx += 512){
    int r = idx >> 7, d = idx & 127;
    int grow = q*TN + T0 + r;
    bput(&s.u.a.Xs[0][0], 320, r, 148 + d, fixnan(hd_in[(size_t)grow*DN + d]));
  }
  for (int idx = tid; idx < 32*12; idx += 512){
    int r = idx / 12, p = idx % 12;
    bput(&s.u.a.Xs[0][0], 320, r, IN_DIM + p, 0.f);
  }
  __syncthreads();

  // ---- Phase 3: proj MFMA  C[32x128] = X[32x288] @ pwt^T ----
  {
    int rA = ll & 15, gK = ll >> 4;
    int rt = wv & 1, nt0 = wv >> 1;
    #pragma unroll
    for (int h = 0; h < 2; ++h){
      int nt = nt0 + h*4;
      float bv = ld<MODE>(pb, nt*16 + rA);
      f32x4 acc = {bv, bv, bv, bv};
      #pragma unroll
      for (int ks = 0; ks < 9; ++ks){
        int k0 = ks*32 + gK*8;
        bf16x8 af = bget8(&s.u.a.Xs[0][0], 320, rt*16 + rA, k0);
        bf16x8 bfv = *(const bf16x8*)((const short*)pwt + (size_t)(nt*16 + rA)*XPAD + k0);
        acc = mfma16(af, bfv, acc);
      }
      #pragma unroll
      for (int r2 = 0; r2 < 4; ++r2)
        s.hdl[rt*16 + gK*4 + r2][nt*16 + rA] = fixnan(acc[r2]);
    }
  }

  // ---- Phase 4: 4 transformer blocks ----
  for (int L = 0; L < 4; ++L){
    __syncthreads();   // hdl ready; Xs/dots dead -> hn/y1 reuse safe
    // LN1 -> hn
    {
      float g0 = ld<MODE>(ln1g, L*DN + ll), g1 = ld<MODE>(ln1g, L*DN + ll + 64);
      float b0 = ld<MODE>(ln1b, L*DN + ll), b1v = ld<MODE>(ln1b, L*DN + ll + 64);
      for (int rr = 0; rr < 4; ++rr){
        int r = wv*4 + rr;
        float a0 = s.hdl[r][ll], a1 = s.hdl[r][ll+64];
        float m = waveReduceSum(a0 + a1) * (1.f/128.f);
        float v0 = a0 - m, v1 = a1 - m;
        float var = waveReduceSum(v0*v0 + v1*v1) * (1.f/128.f);
        float inv = rsqrtf(var + 1e-5f);
        bput(&s.u.b.hn[0][0], 128, r, ll,      v0*inv*g0 + b0);
        bput(&s.u.b.hn[0][0], 128, r, ll + 64, v1*inv*g1 + b1v);
      }
    }
    __syncthreads();
    // depthwise conv over t + residual
    for (int idx = tid; idx < 32*DN; idx += 512){
      int r = idx >> 7, d = idx & 127, t = T0 + r;
      float acc = ld<MODE>(cb, L*DN + d);
      #pragma unroll
      for (int k = 0; k < 5; ++k){
        int tg = t + k - 2, tl = r + k - 2;
        if (tg >= 0 && tg < TN && tl >= 0 && tl < 32)
          acc += bget(&s.u.b.hn[0][0], 128, tl, d) * ld<MODE>(cw, ((size_t)L*DN + d)*5 + k);
      }
      s.hdl[r][d] = fixnan(s.hdl[r][d] + acc);
    }
    __syncthreads();
    // LN2 -> hn
    {
      float g0 = ld<MODE>(ln2g, L*DN + ll), g1 = ld<MODE>(ln2g, L*DN + ll + 64);
      float b0 = ld<MODE>(ln2b, L*DN + ll), b1v = ld<MODE>(ln2b, L*DN + ll + 64);
      for (int rr = 0; rr < 4; ++rr){
        int r = wv*4 + rr;
        float a0 = s.hdl[r][ll], a1 = s.hdl[r][ll+64];
        float m = waveReduceSum(a0 + a1) * (1.f/128.f);
        float v0 = a0 - m, v1 = a1 - m;
        float var = waveReduceSum(v0*v0 + v1*v1) * (1.f/128.f);
        float inv = rsqrtf(var + 1e-5f);
        bput(&s.u.b.hn[0][0], 128, r, ll,      v0*inv*g0 + b0);
        bput(&s.u.b.hn[0][0], 128, r, ll + 64, v1*inv*g1 + b1v);
      }
    }
    __syncthreads();
    // GEMM1 [32x128]@[128x256] + GELU -> y1
    {
      int rA = ll & 15, gK = ll >> 4;
      int rt = wv & 1, nt0 = wv >> 1;
      const short* w1s = (const short*)w1t + (size_t)L*32768;
      #pragma unroll
      for (int h = 0; h < 4; ++h){
        int nt = nt0 + h*4;
        float bv = ld<MODE>(b1, L*256 + nt*16 + rA);
        f32x4 acc = {bv, bv, bv, bv};
        #pragma unroll
        for (int ks = 0; ks < 4; ++ks){
          int k0 = ks*32 + gK*8;
          acc = mfma16(bget8(&s.u.b.hn[0][0], 128, rt*16 + rA, k0),
                       *(const bf16x8*)(w1s + (size_t)(nt*16 + rA)*DN + k0), acc);
        }
        #pragma unroll
        for (int r2 = 0; r2 < 4; ++r2)
          bput(&s.u.b.y1[0][0], 256, rt*16 + gK*4 + r2, nt*16 + rA, gelu_exact(acc[r2]));
      }
    }
    __syncthreads();
    // GEMM2 [32x256]@[256x128] + bias + residual
    {
      int rA = ll & 15, gK = ll >> 4;
      int rt = wv & 1, nt0 = wv >> 1;
      const short* w2s = (const short*)w2t + (size_t)L*32768;
      #pragma unroll
      for (int h = 0; h < 2; ++h){
        int nt = nt0 + h*4;
        float bv = ld<MODE>(b2, L*DN + nt*16 + rA);
        f32x4 acc = {bv, bv, bv, bv};
        #pragma unroll
        for (int ks = 0; ks < 8; ++ks){
          int k0 = ks*32 + gK*8;
          acc = mfma16(bget8(&s.u.b.y1[0][0], 256, rt*16 + rA, k0),
                       *(const bf16x8*)(w2s + (size_t)(nt*16 + rA)*256 + k0), acc);
        }
        #pragma unroll
        for (int r2 = 0; r2 < 4; ++r2){
          int r = rt*16 + gK*4 + r2, cc = nt*16 + rA;
          s.hdl[r][cc] = fixnan(s.hdl[r][cc] + acc[r2]);
        }
      }
    }
  }
  __syncthreads();

  // ---- Phase 5: heads + state update (owned rows only) ----
  for (int rr = 0; rr < 4; ++rr){
    int r = wv*4 + rr, t = T0 + r, grow = q*TN + t;
    bool owned = half ? (r >= 8) : (r < 24);
    float a = ld<MODE>(vb1, ll);
    for (int k = 0; k < DN; ++k)
      a += s.hdl[r][k] * ld<MODE>(vw1, (size_t)k*64 + ll);
    float vis = waveReduceSum(gelu_exact(a) * ld<MODE>(vw2, ll));
    float x0 = s.hdl[r][ll], x1 = s.hdl[r][ll+64];
    float dX = waveReduceSum(x0*ld<MODE>(dwp, ll*2)     + x1*ld<MODE>(dwp, (ll+64)*2));
    float dY = waveReduceSum(x0*ld<MODE>(dwp, ll*2 + 1) + x1*ld<MODE>(dwp, (ll+64)*2 + 1));
    if (owned){
      hd_out[(size_t)grow*DN + ll]      = fixnan(x0);
      hd_out[(size_t)grow*DN + ll + 64] = fixnan(x1);
      if (ll == 0){
        float tx = fixnan(tr_in[2*grow]   + dX + ld<MODE>(dbp, 0));
        float ty = fixnan(tr_in[2*grow+1] + dY + ld<MODE>(dbp, 1));
        tr_out[2*grow] = tx; tr_out[2*grow+1] = ty;
        float vs = fixnan(vi_in[grow] + vis + ld<MODE>(vb2, 0));
        vi_out[grow] = vs;
        if (last){
          if constexpr (MODE == 0){
            ((float*)out)[grow*3 + 0] = tx;
            ((float*)out)[grow*3 + 1] = ty;
            ((float*)out)[grow*3 + 2] = vs * 0.25f;
          } else {
            ((bf16*)out)[grow*3 + 0] = __float2bfloat16(tx);
            ((bf16*)out)[grow*3 + 1] = __float2bfloat16(ty);
            ((bf16*)out)[grow*3 + 2] = __float2bfloat16(vs * 0.25f);
          }
        }
      }
    }
  }
}

__global__ __launch_bounds__(512) void k_iter(const int* __restrict__ mf,
    const void* fmap, const void* query, const void* stride_p,
    const float* tr_in, float* tr_out, const float* vi_in, float* vi_out,
    const float* hd_in, float* hd_out,
    const bf16* pwt, const void* pb,
    const void* ln1g, const void* ln1b, const void* cw, const void* cb,
    const void* ln2g, const void* ln2b,
    const bf16* w1t, const void* b1, const bf16* w2t, const void* b2,
    const void* dwp, const void* dbp,
    const void* vw1, const void* vb1, const void* vw2, const void* vb2,
    void* out, int last)
{
  __shared__ SLds s;
  if (mf[0] == 0)
    iter_impl<0>(s, fmap, query, stride_p, tr_in, tr_out, vi_in, vi_out, hd_in, hd_out,
                 pwt, pb, ln1g, ln1b, cw, cb, ln2g, ln2b, w1t, b1, w2t, b2,
                 dwp, dbp, vw1, vb1, vw2, vb2, out, last);
  else
    iter_impl<1>(s, fmap, query, stride_p, tr_in, tr_out, vi_in, vi_out, hd_in, hd_out,
                 pwt, pb, ln1g, ln1b, cw, cb, ln2g, ln2b, w1t, b1, w2t, b2,
                 dwp, dbp, vw1, vb1, vw2, vb2, out, last);
}

extern "C" void kernel_launch(void* const* d_in, const int* in_sizes, int n_in,
                              void* d_out, int out_size, void* d_ws, size_t ws_size,
                              hipStream_t stream) {
  const void* ct    = d_in[0];
  const void* query = d_in[1];
  const void* fmap  = d_in[2];
  const void* fs    = d_in[3];
  const void* pw    = d_in[4];
  const void* pb    = d_in[5];
  const void* ln1g  = d_in[6];
  const void* ln1b  = d_in[7];
  const void* cw    = d_in[8];
  const void* cb    = d_in[9];
  const void* ln2g  = d_in[10];
  const void* ln2b  = d_in[11];
  const void* w1    = d_in[12];
  const void* b1    = d_in[13];
  const void* w2    = d_in[14];
  const void* b2    = d_in[15];
  const void* dw    = d_in[16];
  const void* db    = d_in[17];
  const void* vw1   = d_in[18];
  const void* vb1   = d_in[19];
  const void* vw2   = d_in[20];
  const void* vb2   = d_in[21];

  char* w = (char*)d_ws;
  int*   mflag = (int*)w;                   w += 256;
  float* tr[2]; float* vi[2]; float* hd[2];
  for (int i = 0; i < 2; ++i){ tr[i] = (float*)w; w += ((size_t)NROWS*2*4 + 255) & ~255ull; }
  for (int i = 0; i < 2; ++i){ vi[i] = (float*)w; w += ((size_t)NROWS*4   + 255) & ~255ull; }
  for (int i = 0; i < 2; ++i){ hd[i] = (float*)w; w += ((size_t)NROWS*DN*4 + 255) & ~255ull; }
  bf16* pwt = (bf16*)w;                     w += ((size_t)128*XPAD*2 + 255) & ~255ull;
  bf16* w1t = (bf16*)w;                     w += ((size_t)4*256*128*2 + 255) & ~255ull;
  bf16* w2t = (bf16*)w;                     w += ((size_t)4*128*256*2 + 255) & ~255ull;

  k_sniff<<<1, 256, 0, stream>>>((const unsigned short*)query, mflag);
  hipMemsetAsync(hd[0], 0, (size_t)NROWS*DN*4, stream);

  int totT = 128*XPAD + 4*256*128 + 4*128*256;
  k_transW<<<(totT + 255)/256, 256, 0, stream>>>(mflag, pw, w1, w2, pwt, w1t, w2t);
  k_init<<<(NROWS + 255)/256, 256, 0, stream>>>(mflag, ct, tr[0], vi[0]);

  for (int it = 0; it < 4; ++it){
    int a = it & 1, b = a ^ 1;
    k_iter<<<256, 512, 0, stream>>>(mflag, fmap, query, fs,
        tr[a], tr[b], vi[a], vi[b], hd[a], hd[b],
        pwt, pb, ln1g, ln1b, cw, cb, ln2g, ln2b,
        w1t, b1, w2t, b2, dw, db, vw1, vb1, vw2, vb2,
        d_out, it == 3);
  }
}

// Round 5
// 450.063 us; speedup vs baseline: 3.7671x; 1.2770x over previous
//
#include <hip/hip_runtime.h>
#include <hip/hip_bf16.h>
#include <math.h>

#define QN 128
#define TN 48
#define CN 64
#define HN 96
#define WN 128
#define DN 128
#define KK 49
#define IN_DIM 276
#define XPAD 288
#define NROWS (QN*TN)
#define PI_F 3.14159265358979323846f

typedef __hip_bfloat16 bf16;
typedef unsigned short u16;
using bf16x8 = __attribute__((ext_vector_type(8))) short;
using f32x4  = __attribute__((ext_vector_type(4))) float;

__device__ inline float fixnan(float x){ return (x == x && fabsf(x) < 1e30f) ? x : 0.f; }

template<int MODE> __device__ inline float ld(const void* p, size_t i){
  if constexpr (MODE == 0) return ((const float*)p)[i];
  else {
    unsigned int u = ((const unsigned short*)p)[i];
    return __uint_as_float(u << 16);
  }
}

__device__ inline short f2b(float x){
  __hip_bfloat16 h = __float2bfloat16(x);
  return *reinterpret_cast<short*>(&h);
}
__device__ inline float b2f16(u16 u){ return __uint_as_float(((unsigned int)u) << 16); }

__device__ inline float waveReduceSum(float v){
  #pragma unroll
  for (int off = 32; off > 0; off >>= 1) v += __shfl_xor(v, off, 64);
  return v;
}

__device__ inline float gelu_exact(float x){
  return 0.5f * x * (1.f + erff(x * 0.70710678118654752440f));
}

__device__ inline f32x4 mfma16(bf16x8 a, bf16x8 b, f32x4 c){
  return __builtin_amdgcn_mfma_f32_16x16x32_bf16(a, b, c, 0, 0, 0);
}

__device__ inline float decode_stride(const void* p){
  int iv = *(const int*)p;
  if (iv >= 1 && iv <= (1 << 20)) return (float)iv;
  float fv = __int_as_float(iv);
  if (fv == fv && fv >= 0.25f && fv <= 1048576.f) return fv;
  unsigned int lo = ((unsigned int)(*(const unsigned short*)p)) << 16;
  float bv = __uint_as_float(lo);
  if (bv == bv && bv >= 0.25f && bv <= 1048576.f) return bv;
  return 4.f;
}

__device__ inline void bput(short* base, int stride_sh, int r, int k, float v){
  *(short*)((char*)base + (size_t)r*stride_sh*2 + ((2*k) ^ ((r & 7) << 4))) = f2b(v);
}
__device__ inline float bget(const short* base, int stride_sh, int r, int k){
  unsigned short u = *(const unsigned short*)((const char*)base + (size_t)r*stride_sh*2 + ((2*k) ^ ((r & 7) << 4)));
  return __uint_as_float(((unsigned int)u) << 16);
}
__device__ inline bf16x8 bget8(const short* base, int stride_sh, int r, int k0){
  return *(const bf16x8*)((const char*)base + (size_t)r*stride_sh*2 + ((2*k0) ^ ((r & 7) << 4)));
}

struct SLds {
  float qv[CN];
  float sdx[32], sdy[32], sc0[32], sc1[32];
  float hdl[32][132];
  union {
    struct { float dots[32][64]; short Xs[32][320]; } a;
    struct { short hn[32][128]; short y1[32][256]; } b;
  } u;
};

// ---- dtype sniffer ----
__global__ __launch_bounds__(256) void k_sniff(const unsigned short* __restrict__ q,
                                               int* __restrict__ flag){
  __shared__ int cnt;
  if (threadIdx.x == 0) cnt = 0;
  __syncthreads();
  int good = 0;
  for (int i = threadIdx.x; i < 8192; i += 256){
    float v = __uint_as_float(((unsigned int)q[i]) << 16);
    float a = fabsf(v);
    if (a > 1e-3f && a < 30.f) good++;
  }
  atomicAdd(&cnt, good);
  __syncthreads();
  if (threadIdx.x == 0) flag[0] = (cnt > 6500) ? 1 : 0;
}

// ---- fmap transpose: [t][c][y][x] -> [t][y][x][c] bf16 ----
template<int MODE>
__device__ void transpose_impl(u16 (*tile)[130], const void* fmap, u16* fmapT){
  int t = blockIdx.x / HN, y = blockIdx.x % HN;
  int tid = threadIdx.x, wv = tid >> 6, lane = tid & 63;
  #pragma unroll 4
  for (int ci = 0; ci < 16; ++ci){
    int c = ci*4 + wv;
    size_t base = (((size_t)t*CN + c)*HN + y)*WN;
    if constexpr (MODE == 1){
      const u16* fp = (const u16*)fmap + base + 2*lane;
      tile[c][2*lane]   = fp[0];
      tile[c][2*lane+1] = fp[1];
    } else {
      const float* fp = (const float*)fmap + base + 2*lane;
      tile[c][2*lane]   = (u16)f2b(fp[0]);
      tile[c][2*lane+1] = (u16)f2b(fp[1]);
    }
  }
  __syncthreads();
  u16* op = fmapT + (((size_t)t*HN + y)*WN)*CN + lane;
  #pragma unroll 4
  for (int xi = 0; xi < 32; ++xi){
    int x = xi*4 + wv;
    op[(size_t)x*CN] = tile[lane][x];
  }
}
__global__ __launch_bounds__(256) void k_transpose(const int* __restrict__ mf,
    const void* fmap, u16* fmapT){
  __shared__ u16 tile[64][130];
  if (mf[0] == 0) transpose_impl<0>(tile, fmap, fmapT);
  else            transpose_impl<1>(tile, fmap, fmapT);
}

// ---- weight transposes ----
template<int MODE>
__device__ void transW_impl(int idx, const void* pw, const void* w1, const void* w2,
                            bf16* pwt, bf16* w1t, bf16* w2t){
  if (idx < 128*XPAD){
    int n = idx / XPAD, kk = idx % XPAD;
    float v = (kk < IN_DIM) ? ld<MODE>(pw, (size_t)kk*DN + n) : 0.f;
    ((short*)pwt)[idx] = f2b(v);
  } else if (idx < 128*XPAD + 4*256*128){
    int i2 = idx - 128*XPAD;
    int k = i2 & 127, n = (i2 >> 7) & 255, l = i2 >> 15;
    ((short*)w1t)[i2] = f2b(ld<MODE>(w1, (size_t)l*32768 + (size_t)k*256 + n));
  } else {
    int i3 = idx - 128*XPAD - 4*256*128;
    int k = i3 & 255, n = (i3 >> 8) & 127, l = i3 >> 15;
    ((short*)w2t)[i3] = f2b(ld<MODE>(w2, (size_t)l*32768 + (size_t)k*128 + n));
  }
}
__global__ __launch_bounds__(256) void k_transW(const int* __restrict__ mf,
    const void* pw, const void* w1, const void* w2,
    bf16* pwt, bf16* w1t, bf16* w2t){
  int idx = blockIdx.x*256 + threadIdx.x;
  int total = 128*XPAD + 4*256*128 + 4*128*256;
  if (idx >= total) return;
  if (mf[0] == 0) transW_impl<0>(idx, pw, w1, w2, pwt, w1t, w2t);
  else            transW_impl<1>(idx, pw, w1, w2, pwt, w1t, w2t);
}

// ---- init ----
template<int MODE>
__device__ void init_impl(const void* ct, float* tracks, float* vis_sum){
  int i = blockIdx.x * 256 + threadIdx.x;
  if (i < NROWS){
    tracks[2*i]   = fixnan(ld<MODE>(ct, 2*i));
    tracks[2*i+1] = fixnan(ld<MODE>(ct, 2*i+1));
    vis_sum[i] = 0.f;
  }
}
__global__ __launch_bounds__(256) void k_init(const int* __restrict__ mf,
    const void* ct, float* tracks, float* vis_sum){
  if (mf[0] == 0) init_impl<0>(ct, tracks, vis_sum);
  else            init_impl<1>(ct, tracks, vis_sum);
}

// ==== fused per-iteration kernel ====
template<int MODE, int FAST>
__device__ void iter_impl(SLds& s,
    const void* fmap, const u16* fmapT, const void* query, const void* stride_p,
    const float* __restrict__ tr_in, float* __restrict__ tr_out,
    const float* __restrict__ vi_in, float* __restrict__ vi_out,
    const float* __restrict__ hd_in, float* __restrict__ hd_out,
    const bf16* pwt, const void* pb,
    const void* ln1g, const void* ln1b, const void* cw, const void* cb,
    const void* ln2g, const void* ln2b,
    const bf16* w1t, const void* b1, const bf16* w2t, const void* b2,
    const void* dwp, const void* dbp,
    const void* vw1, const void* vb1, const void* vw2, const void* vb2,
    void* out, int last)
{
  int bid = blockIdx.x;
  int q = bid >> 1, half = bid & 1, T0 = half * 16;
  int tid = threadIdx.x, wv = tid >> 6, ll = tid & 63;

  if (tid < CN) s.qv[tid] = ld<MODE>(query, q*CN + tid);
  float fs = decode_stride(stride_p);
  __syncthreads();

  // ---- Phase 1: corr dots ----
  if constexpr (FAST){
    float qv8[8];
    #pragma unroll
    for (int u = 0; u < 8; ++u) qv8[u] = s.qv[(ll & 7)*8 + u];
    for (int rr = 0; rr < 4; ++rr){
      int r = wv*4 + rr, t = T0 + r, grow = q*TN + t;
      float c0 = fixnan(tr_in[2*grow]), c1 = fixnan(tr_in[2*grow+1]);
      float px = fminf(fmaxf(c0 / fs, -1e6f), 1e6f);
      float py = fminf(fmaxf(c1 / fs, -1e6f), 1e6f);
      float fx0 = floorf(px), fy0 = floorf(py);
      if (ll == 0){ s.sdx[r] = px - fx0; s.sdy[r] = py - fy0; s.sc0[r] = c0; s.sc1[r] = c1; }
      int x0 = (int)fx0 - 3, y0 = (int)fy0 - 3;
      s.u.a.dots[r][ll] = 0.f;
      if (x0 <= 127 && x0 + 7 >= 0){
        int x0c = min(max(x0, 0), WN - 8);
        int sh = x0c - x0;                    // tap index i = i' + sh
        int ip = ll >> 3;
        int i = ip + sh;
        bool wr = ((ll & 7) == 0) && (i >= 0) && (i < 8);
        #pragma unroll
        for (int j = 0; j < 8; ++j){
          int yj = y0 + j;
          if (yj < 0 || yj >= HN) continue;
          const u16* blk = fmapT + ((((size_t)t*HN + yj)*WN + x0c) << 6);
          bf16x8 v = *(const bf16x8*)(blk + ll*8);
          float p = 0.f;
          #pragma unroll
          for (int u = 0; u < 8; ++u) p += qv8[u] * b2f16((u16)v[u]);
          p += __shfl_xor(p, 1, 64);
          p += __shfl_xor(p, 2, 64);
          p += __shfl_xor(p, 4, 64);
          if (wr) s.u.a.dots[r][j*8 + i] = p;
        }
      }
    }
  } else {
    for (int rr = 0; rr < 4; ++rr){
      int r = wv*4 + rr, t = T0 + r, grow = q*TN + t;
      float c0 = fixnan(tr_in[2*grow]), c1 = fixnan(tr_in[2*grow+1]);
      float px = fminf(fmaxf(c0 / fs, -1e6f), 1e6f);
      float py = fminf(fmaxf(c1 / fs, -1e6f), 1e6f);
      float fx0 = floorf(px), fy0 = floorf(py);
      if (ll == 0){ s.sdx[r] = px - fx0; s.sdy[r] = py - fy0; s.sc0[r] = c0; s.sc1[r] = c1; }
      int bx = (int)fx0, by = (int)fy0;
      int j = ll >> 3, i = ll & 7;
      int xi = bx + i - 3, yi = by + j - 3;
      float dot = 0.f;
      if (xi >= 0 && xi < WN && yi >= 0 && yi < HN){
        size_t base = ((size_t)t*CN)*HN*WN + (size_t)yi*WN + xi;
        #pragma unroll 8
        for (int c = 0; c < CN; ++c)
          dot += s.qv[c] * ld<MODE>(fmap, base + (size_t)c*HN*WN);
      }
      s.u.a.dots[r][ll] = dot;
    }
  }
  __syncthreads();

  // ---- Phase 2: assemble X ----
  for (int idx = tid; idx < 32*KK; idx += 512){
    int r = idx / KK, kk = idx % KK, oy = kk / 7, ox = kk % 7;
    float dx = s.sdx[r], dy = s.sdy[r];
    const float* dr = s.u.a.dots[r];
    float v = (1.f-dx)*(1.f-dy)*dr[oy*8+ox]     + dx*(1.f-dy)*dr[oy*8+ox+1]
            + (1.f-dx)*dy*dr[(oy+1)*8+ox]       + dx*dy*dr[(oy+1)*8+ox+1];
    bput(&s.u.a.Xs[0][0], 320, r, kk, fixnan(v));
  }
  for (int idx = tid; idx < 32*3; idx += 512){
    int r = idx / 3, cd = idx % 3;
    float v = (cd == 0) ? s.sc0[r] : (cd == 1 ? s.sc1[r] : (float)(T0+r)/(float)(TN-1));
    bput(&s.u.a.Xs[0][0], 320, r, KK + cd, v);
  }
  for (int idx = tid; idx < 32*96; idx += 512){
    int r = idx / 96, j = idx % 96, coord = j >> 5, rm = j & 31, band = rm & 15;
    float cv = (coord == 0) ? s.sc0[r] : (coord == 1 ? s.sc1[r] : (float)(T0+r)/(float)(TN-1));
    float a = cv * exp2f(0.6f*(float)band) * PI_F;
    float v = (rm < 16) ? sinf(a) : cosf(a);
    bput(&s.u.a.Xs[0][0], 320, r, KK + 3 + coord*32 + rm, fixnan(v));
  }
  for (int idx = tid; idx < 32*DN; idx += 512){
    int r = idx >> 7, d = idx & 127;
    int grow = q*TN + T0 + r;
    bput(&s.u.a.Xs[0][0], 320, r, 148 + d, fixnan(hd_in[(size_t)grow*DN + d]));
  }
  for (int idx = tid; idx < 32*12; idx += 512){
    int r = idx / 12, p = idx % 12;
    bput(&s.u.a.Xs[0][0], 320, r, IN_DIM + p, 0.f);
  }
  __syncthreads();

  // ---- Phase 3: proj MFMA ----
  {
    int rA = ll & 15, gK = ll >> 4;
    int rt = wv & 1, nt0 = wv >> 1;
    #pragma unroll
    for (int h = 0; h < 2; ++h){
      int nt = nt0 + h*4;
      float bv = ld<MODE>(pb, nt*16 + rA);
      f32x4 acc = {bv, bv, bv, bv};
      #pragma unroll
      for (int ks = 0; ks < 9; ++ks){
        int k0 = ks*32 + gK*8;
        bf16x8 af = bget8(&s.u.a.Xs[0][0], 320, rt*16 + rA, k0);
        bf16x8 bfv = *(const bf16x8*)((const short*)pwt + (size_t)(nt*16 + rA)*XPAD + k0);
        acc = mfma16(af, bfv, acc);
      }
      #pragma unroll
      for (int r2 = 0; r2 < 4; ++r2)
        s.hdl[rt*16 + gK*4 + r2][nt*16 + rA] = fixnan(acc[r2]);
    }
  }

  // ---- Phase 4: 4 transformer blocks ----
  for (int L = 0; L < 4; ++L){
    __syncthreads();
    {
      float g0 = ld<MODE>(ln1g, L*DN + ll), g1 = ld<MODE>(ln1g, L*DN + ll + 64);
      float b0 = ld<MODE>(ln1b, L*DN + ll), b1v = ld<MODE>(ln1b, L*DN + ll + 64);
      for (int rr = 0; rr < 4; ++rr){
        int r = wv*4 + rr;
        float a0 = s.hdl[r][ll], a1 = s.hdl[r][ll+64];
        float m = waveReduceSum(a0 + a1) * (1.f/128.f);
        float v0 = a0 - m, v1 = a1 - m;
        float var = waveReduceSum(v0*v0 + v1*v1) * (1.f/128.f);
        float inv = rsqrtf(var + 1e-5f);
        bput(&s.u.b.hn[0][0], 128, r, ll,      v0*inv*g0 + b0);
        bput(&s.u.b.hn[0][0], 128, r, ll + 64, v1*inv*g1 + b1v);
      }
    }
    __syncthreads();
    for (int idx = tid; idx < 32*DN; idx += 512){
      int r = idx >> 7, d = idx & 127, t = T0 + r;
      float acc = ld<MODE>(cb, L*DN + d);
      #pragma unroll
      for (int k = 0; k < 5; ++k){
        int tg = t + k - 2, tl = r + k - 2;
        if (tg >= 0 && tg < TN && tl >= 0 && tl < 32)
          acc += bget(&s.u.b.hn[0][0], 128, tl, d) * ld<MODE>(cw, ((size_t)L*DN + d)*5 + k);
      }
      s.hdl[r][d] = fixnan(s.hdl[r][d] + acc);
    }
    __syncthreads();
    {
      float g0 = ld<MODE>(ln2g, L*DN + ll), g1 = ld<MODE>(ln2g, L*DN + ll + 64);
      float b0 = ld<MODE>(ln2b, L*DN + ll), b1v = ld<MODE>(ln2b, L*DN + ll + 64);
      for (int rr = 0; rr < 4; ++rr){
        int r = wv*4 + rr;
        float a0 = s.hdl[r][ll], a1 = s.hdl[r][ll+64];
        float m = waveReduceSum(a0 + a1) * (1.f/128.f);
        float v0 = a0 - m, v1 = a1 - m;
        float var = waveReduceSum(v0*v0 + v1*v1) * (1.f/128.f);
        float inv = rsqrtf(var + 1e-5f);
        bput(&s.u.b.hn[0][0], 128, r, ll,      v0*inv*g0 + b0);
        bput(&s.u.b.hn[0][0], 128, r, ll + 64, v1*inv*g1 + b1v);
      }
    }
    __syncthreads();
    {
      int rA = ll & 15, gK = ll >> 4;
      int rt = wv & 1, nt0 = wv >> 1;
      const short* w1s = (const short*)w1t + (size_t)L*32768;
      #pragma unroll
      for (int h = 0; h < 4; ++h){
        int nt = nt0 + h*4;
        float bv = ld<MODE>(b1, L*256 + nt*16 + rA);
        f32x4 acc = {bv, bv, bv, bv};
        #pragma unroll
        for (int ks = 0; ks < 4; ++ks){
          int k0 = ks*32 + gK*8;
          acc = mfma16(bget8(&s.u.b.hn[0][0], 128, rt*16 + rA, k0),
                       *(const bf16x8*)(w1s + (size_t)(nt*16 + rA)*DN + k0), acc);
        }
        #pragma unroll
        for (int r2 = 0; r2 < 4; ++r2)
          bput(&s.u.b.y1[0][0], 256, rt*16 + gK*4 + r2, nt*16 + rA, gelu_exact(acc[r2]));
      }
    }
    __syncthreads();
    {
      int rA = ll & 15, gK = ll >> 4;
      int rt = wv & 1, nt0 = wv >> 1;
      const short* w2s = (const short*)w2t + (size_t)L*32768;
      #pragma unroll
      for (int h = 0; h < 2; ++h){
        int nt = nt0 + h*4;
        float bv = ld<MODE>(b2, L*DN + nt*16 + rA);
        f32x4 acc = {bv, bv, bv, bv};
        #pragma unroll
        for (int ks = 0; ks < 8; ++ks){
          int k0 = ks*32 + gK*8;
          acc = mfma16(bget8(&s.u.b.y1[0][0], 256, rt*16 + rA, k0),
                       *(const bf16x8*)(w2s + (size_t)(nt*16 + rA)*256 + k0), acc);
        }
        #pragma unroll
        for (int r2 = 0; r2 < 4; ++r2){
          int r = rt*16 + gK*4 + r2, cc = nt*16 + rA;
          s.hdl[r][cc] = fixnan(s.hdl[r][cc] + acc[r2]);
        }
      }
    }
  }
  __syncthreads();

  // ---- Phase 5: heads ----
  for (int rr = 0; rr < 4; ++rr){
    int r = wv*4 + rr, t = T0 + r, grow = q*TN + t;
    bool owned = half ? (r >= 8) : (r < 24);
    float a = ld<MODE>(vb1, ll);
    for (int k = 0; k < DN; ++k)
      a += s.hdl[r][k] * ld<MODE>(vw1, (size_t)k*64 + ll);
    float vis = waveReduceSum(gelu_exact(a) * ld<MODE>(vw2, ll));
    float x0 = s.hdl[r][ll], x1 = s.hdl[r][ll+64];
    float dX = waveReduceSum(x0*ld<MODE>(dwp, ll*2)     + x1*ld<MODE>(dwp, (ll+64)*2));
    float dY = waveReduceSum(x0*ld<MODE>(dwp, ll*2 + 1) + x1*ld<MODE>(dwp, (ll+64)*2 + 1));
    if (owned){
      hd_out[(size_t)grow*DN + ll]      = fixnan(x0);
      hd_out[(size_t)grow*DN + ll + 64] = fixnan(x1);
      if (ll == 0){
        float tx = fixnan(tr_in[2*grow]   + dX + ld<MODE>(dbp, 0));
        float ty = fixnan(tr_in[2*grow+1] + dY + ld<MODE>(dbp, 1));
        tr_out[2*grow] = tx; tr_out[2*grow+1] = ty;
        float vs = fixnan(vi_in[grow] + vis + ld<MODE>(vb2, 0));
        vi_out[grow] = vs;
        if (last){
          if constexpr (MODE == 0){
            ((float*)out)[grow*3 + 0] = tx;
            ((float*)out)[grow*3 + 1] = ty;
            ((float*)out)[grow*3 + 2] = vs * 0.25f;
          } else {
            ((bf16*)out)[grow*3 + 0] = __float2bfloat16(tx);
            ((bf16*)out)[grow*3 + 1] = __float2bfloat16(ty);
            ((bf16*)out)[grow*3 + 2] = __float2bfloat16(vs * 0.25f);
          }
        }
      }
    }
  }
}

template<int FAST>
__global__ __launch_bounds__(512) void k_iter(const int* __restrict__ mf,
    const void* fmap, const u16* fmapT, const void* query, const void* stride_p,
    const float* tr_in, float* tr_out, const float* vi_in, float* vi_out,
    const float* hd_in, float* hd_out,
    const bf16* pwt, const void* pb,
    const void* ln1g, const void* ln1b, const void* cw, const void* cb,
    const void* ln2g, const void* ln2b,
    const bf16* w1t, const void* b1, const bf16* w2t, const void* b2,
    const void* dwp, const void* dbp,
    const void* vw1, const void* vb1, const void* vw2, const void* vb2,
    void* out, int last)
{
  __shared__ SLds s;
  if (mf[0] == 0)
    iter_impl<0, FAST>(s, fmap, fmapT, query, stride_p, tr_in, tr_out, vi_in, vi_out, hd_in, hd_out,
                 pwt, pb, ln1g, ln1b, cw, cb, ln2g, ln2b, w1t, b1, w2t, b2,
                 dwp, dbp, vw1, vb1, vw2, vb2, out, last);
  else
    iter_impl<1, FAST>(s, fmap, fmapT, query, stride_p, tr_in, tr_out, vi_in, vi_out, hd_in, hd_out,
                 pwt, pb, ln1g, ln1b, cw, cb, ln2g, ln2b, w1t, b1, w2t, b2,
                 dwp, dbp, vw1, vb1, vw2, vb2, out, last);
}

extern "C" void kernel_launch(void* const* d_in, const int* in_sizes, int n_in,
                              void* d_out, int out_size, void* d_ws, size_t ws_size,
                              hipStream_t stream) {
  const void* ct    = d_in[0];
  const void* query = d_in[1];
  const void* fmap  = d_in[2];
  const void* fs    = d_in[3];
  const void* pw    = d_in[4];
  const void* pb    = d_in[5];
  const void* ln1g  = d_in[6];
  const void* ln1b  = d_in[7];
  const void* cw    = d_in[8];
  const void* cb    = d_in[9];
  const void* ln2g  = d_in[10];
  const void* ln2b  = d_in[11];
  const void* w1    = d_in[12];
  const void* b1    = d_in[13];
  const void* w2    = d_in[14];
  const void* b2    = d_in[15];
  const void* dw    = d_in[16];
  const void* db    = d_in[17];
  const void* vw1   = d_in[18];
  const void* vb1   = d_in[19];
  const void* vw2   = d_in[20];
  const void* vb2   = d_in[21];

  char* w0 = (char*)d_ws;
  char* w = w0;
  int*   mflag = (int*)w;                   w += 256;
  float* tr[2]; float* vi[2]; float* hd[2];
  for (int i = 0; i < 2; ++i){ tr[i] = (float*)w; w += ((size_t)NROWS*2*4 + 255) & ~255ull; }
  for (int i = 0; i < 2; ++i){ vi[i] = (float*)w; w += ((size_t)NROWS*4   + 255) & ~255ull; }
  for (int i = 0; i < 2; ++i){ hd[i] = (float*)w; w += ((size_t)NROWS*DN*4 + 255) & ~255ull; }
  bf16* pwt = (bf16*)w;                     w += ((size_t)128*XPAD*2 + 255) & ~255ull;
  bf16* w1t = (bf16*)w;                     w += ((size_t)4*256*128*2 + 255) & ~255ull;
  bf16* w2t = (bf16*)w;                     w += ((size_t)4*128*256*2 + 255) & ~255ull;
  u16*  fmapT = (u16*)w;                    w += ((size_t)TN*HN*WN*CN*2 + 255) & ~255ull;

  bool fast = ((size_t)(w - w0) <= ws_size);

  k_sniff<<<1, 256, 0, stream>>>((const unsigned short*)query, mflag);
  hipMemsetAsync(hd[0], 0, (size_t)NROWS*DN*4, stream);

  int totT = 128*XPAD + 4*256*128 + 4*128*256;
  k_transW<<<(totT + 255)/256, 256, 0, stream>>>(mflag, pw, w1, w2, pwt, w1t, w2t);
  k_init<<<(NROWS + 255)/256, 256, 0, stream>>>(mflag, ct, tr[0], vi[0]);
  if (fast)
    k_transpose<<<TN*HN, 256, 0, stream>>>(mflag, fmap, fmapT);

  for (int it = 0; it < 4; ++it){
    int a = it & 1, b = a ^ 1;
    if (fast)
      k_iter<1><<<256, 512, 0, stream>>>(mflag, fmap, fmapT, query, fs,
          tr[a], tr[b], vi[a], vi[b], hd[a], hd[b],
          pwt, pb, ln1g, ln1b, cw, cb, ln2g, ln2b,
          w1t, b1, w2t, b2, dw, db, vw1, vb1, vw2, vb2,
          d_out, it == 3);
    else
      k_iter<0><<<256, 512, 0, stream>>>(mflag, fmap, fmapT, query, fs,
          tr[a], tr[b], vi[a], vi[b], hd[a], hd[b],
          pwt, pb, ln1g, ln1b, cw, cb, ln2g, ln2b,
          w1t, b1, w2t, b2, dw, db, vw1, vb1, vw2, vb2,
          d_out, it == 3);
  }
}

// Round 6
// 383.063 us; speedup vs baseline: 4.4259x; 1.1749x over previous
//
#include <hip/hip_runtime.h>
#include <hip/hip_bf16.h>
#include <math.h>

#define QN 128
#define TN 48
#define CN 64
#define HN 96
#define WN 128
#define DN 128
#define KK 49
#define IN_DIM 276
#define XPAD 288
#define NROWS (QN*TN)
#define PI_F 3.14159265358979323846f

typedef __hip_bfloat16 bf16;
typedef unsigned short u16;
using bf16x8 = __attribute__((ext_vector_type(8))) short;
using f32x4  = __attribute__((ext_vector_type(4))) float;

__device__ inline float fixnan(float x){ return (x == x && fabsf(x) < 1e30f) ? x : 0.f; }

template<int MODE> __device__ inline float ld(const void* p, size_t i){
  if constexpr (MODE == 0) return ((const float*)p)[i];
  else {
    unsigned int u = ((const unsigned short*)p)[i];
    return __uint_as_float(u << 16);
  }
}

__device__ inline short f2b(float x){
  __hip_bfloat16 h = __float2bfloat16(x);
  return *reinterpret_cast<short*>(&h);
}
__device__ inline float b2f16(u16 u){ return __uint_as_float(((unsigned int)u) << 16); }

__device__ inline float waveReduceSum(float v){
  #pragma unroll
  for (int off = 32; off > 0; off >>= 1) v += __shfl_xor(v, off, 64);
  return v;
}

__device__ inline float gelu_exact(float x){
  return 0.5f * x * (1.f + erff(x * 0.70710678118654752440f));
}

__device__ inline f32x4 mfma16(bf16x8 a, bf16x8 b, f32x4 c){
  return __builtin_amdgcn_mfma_f32_16x16x32_bf16(a, b, c, 0, 0, 0);
}

__device__ inline float decode_stride(const void* p){
  int iv = *(const int*)p;
  if (iv >= 1 && iv <= (1 << 20)) return (float)iv;
  float fv = __int_as_float(iv);
  if (fv == fv && fv >= 0.25f && fv <= 1048576.f) return fv;
  unsigned int lo = ((unsigned int)(*(const unsigned short*)p)) << 16;
  float bv = __uint_as_float(lo);
  if (bv == bv && bv >= 0.25f && bv <= 1048576.f) return bv;
  return 4.f;
}

__device__ inline void bput(short* base, int stride_sh, int r, int k, float v){
  *(short*)((char*)base + (size_t)r*stride_sh*2 + ((2*k) ^ ((r & 7) << 4))) = f2b(v);
}
__device__ inline float bget(const short* base, int stride_sh, int r, int k){
  unsigned short u = *(const unsigned short*)((const char*)base + (size_t)r*stride_sh*2 + ((2*k) ^ ((r & 7) << 4)));
  return __uint_as_float(((unsigned int)u) << 16);
}
__device__ inline bf16x8 bget8(const short* base, int stride_sh, int r, int k0){
  return *(const bf16x8*)((const char*)base + (size_t)r*stride_sh*2 + ((2*k0) ^ ((r & 7) << 4)));
}

struct SLds {
  float qv[CN];
  float sdx[32], sdy[32], sc0[32], sc1[32];
  float hdl[32][132];
  union {
    struct { float dots[32][64]; short Xs[32][320]; } a;
    struct { short hn[32][128]; short y1[32][256]; } b;
  } u;
};

// ---- dtype sniffer ----
__global__ __launch_bounds__(256) void k_sniff(const unsigned short* __restrict__ q,
                                               int* __restrict__ flag){
  __shared__ int cnt;
  if (threadIdx.x == 0) cnt = 0;
  __syncthreads();
  int good = 0;
  for (int i = threadIdx.x; i < 8192; i += 256){
    float v = __uint_as_float(((unsigned int)q[i]) << 16);
    float a = fabsf(v);
    if (a > 1e-3f && a < 30.f) good++;
  }
  atomicAdd(&cnt, good);
  __syncthreads();
  if (threadIdx.x == 0) flag[0] = (cnt > 6500) ? 1 : 0;
}

// ---- fmap transpose: [t][c][y][x] -> [t][y][x][c] bf16 ----
template<int MODE>
__device__ void transpose_impl(u16 (*tile)[130], const void* fmap, u16* fmapT){
  int t = blockIdx.x / HN, y = blockIdx.x % HN;
  int tid = threadIdx.x, wv = tid >> 6, lane = tid & 63;
  #pragma unroll 4
  for (int ci = 0; ci < 16; ++ci){
    int c = ci*4 + wv;
    size_t base = (((size_t)t*CN + c)*HN + y)*WN;
    if constexpr (MODE == 1){
      const u16* fp = (const u16*)fmap + base + 2*lane;
      tile[c][2*lane]   = fp[0];
      tile[c][2*lane+1] = fp[1];
    } else {
      const float* fp = (const float*)fmap + base + 2*lane;
      tile[c][2*lane]   = (u16)f2b(fp[0]);
      tile[c][2*lane+1] = (u16)f2b(fp[1]);
    }
  }
  __syncthreads();
  u16* op = fmapT + (((size_t)t*HN + y)*WN)*CN + lane;
  #pragma unroll 4
  for (int xi = 0; xi < 32; ++xi){
    int x = xi*4 + wv;
    op[(size_t)x*CN] = tile[lane][x];
  }
}
__global__ __launch_bounds__(256) void k_transpose(const int* __restrict__ mf,
    const void* fmap, u16* fmapT){
  __shared__ u16 tile[64][130];
  if (mf[0] == 0) transpose_impl<0>(tile, fmap, fmapT);
  else            transpose_impl<1>(tile, fmap, fmapT);
}

// ---- weight transposes ----
#define TW_PW   (128*XPAD)
#define TW_W1   (4*256*128)
#define TW_W2   (4*128*256)
#define TW_VW1  (64*128)
#define TW_TOT  (TW_PW + TW_W1 + TW_W2 + TW_VW1)
template<int MODE>
__device__ void transW_impl(int idx, const void* pw, const void* w1, const void* w2,
                            const void* vw1,
                            bf16* pwt, bf16* w1t, bf16* w2t, bf16* vw1t){
  if (idx < TW_PW){
    int n = idx / XPAD, kk = idx % XPAD;
    float v = (kk < IN_DIM) ? ld<MODE>(pw, (size_t)kk*DN + n) : 0.f;
    ((short*)pwt)[idx] = f2b(v);
  } else if (idx < TW_PW + TW_W1){
    int i2 = idx - TW_PW;
    int k = i2 & 127, n = (i2 >> 7) & 255, l = i2 >> 15;
    ((short*)w1t)[i2] = f2b(ld<MODE>(w1, (size_t)l*32768 + (size_t)k*256 + n));
  } else if (idx < TW_PW + TW_W1 + TW_W2){
    int i3 = idx - TW_PW - TW_W1;
    int k = i3 & 255, n = (i3 >> 8) & 127, l = i3 >> 15;
    ((short*)w2t)[i3] = f2b(ld<MODE>(w2, (size_t)l*32768 + (size_t)k*128 + n));
  } else {
    int i4 = idx - TW_PW - TW_W1 - TW_W2;
    int n = i4 >> 7, k = i4 & 127;
    ((short*)vw1t)[i4] = f2b(ld<MODE>(vw1, (size_t)k*64 + n));
  }
}
__global__ __launch_bounds__(256) void k_transW(const int* __restrict__ mf,
    const void* pw, const void* w1, const void* w2, const void* vw1,
    bf16* pwt, bf16* w1t, bf16* w2t, bf16* vw1t){
  int idx = blockIdx.x*256 + threadIdx.x;
  if (idx >= TW_TOT) return;
  if (mf[0] == 0) transW_impl<0>(idx, pw, w1, w2, vw1, pwt, w1t, w2t, vw1t);
  else            transW_impl<1>(idx, pw, w1, w2, vw1, pwt, w1t, w2t, vw1t);
}

// ---- init ----
template<int MODE>
__device__ void init_impl(const void* ct, float* tracks, float* vis_sum){
  int i = blockIdx.x * 256 + threadIdx.x;
  if (i < NROWS){
    tracks[2*i]   = fixnan(ld<MODE>(ct, 2*i));
    tracks[2*i+1] = fixnan(ld<MODE>(ct, 2*i+1));
    vis_sum[i] = 0.f;
  }
}
__global__ __launch_bounds__(256) void k_init(const int* __restrict__ mf,
    const void* ct, float* tracks, float* vis_sum){
  if (mf[0] == 0) init_impl<0>(ct, tracks, vis_sum);
  else            init_impl<1>(ct, tracks, vis_sum);
}

// ==== fused per-iteration kernel ====
template<int MODE, int FAST>
__device__ void iter_impl(SLds& s,
    const void* fmap, const u16* fmapT, const void* query, const void* stride_p,
    const float* __restrict__ tr_in, float* __restrict__ tr_out,
    const float* __restrict__ vi_in, float* __restrict__ vi_out,
    const float* __restrict__ hd_in, float* __restrict__ hd_out,
    const bf16* pwt, const void* pb,
    const void* ln1g, const void* ln1b, const void* cw, const void* cb,
    const void* ln2g, const void* ln2b,
    const bf16* w1t, const void* b1, const bf16* w2t, const void* b2,
    const void* dwp, const void* dbp,
    const bf16* vw1t, const void* vb1, const void* vw2, const void* vb2,
    void* out, int last)
{
  int bid = blockIdx.x;
  int q = bid >> 1, half = bid & 1, T0 = half * 16;
  int tid = threadIdx.x, wv = tid >> 6, ll = tid & 63;

  if (tid < CN) s.qv[tid] = ld<MODE>(query, q*CN + tid);
  float fs = decode_stride(stride_p);
  __syncthreads();

  // ---- Phase 1: corr dots ----
  if constexpr (FAST){
    float qv8[8];
    #pragma unroll
    for (int u = 0; u < 8; ++u) qv8[u] = s.qv[(ll & 7)*8 + u];
    #pragma unroll
    for (int rr = 0; rr < 4; ++rr){
      int r = wv*4 + rr, t = T0 + r, grow = q*TN + t;
      float c0 = fixnan(tr_in[2*grow]), c1 = fixnan(tr_in[2*grow+1]);
      float px = fminf(fmaxf(c0 / fs, -1e6f), 1e6f);
      float py = fminf(fmaxf(c1 / fs, -1e6f), 1e6f);
      float fx0 = floorf(px), fy0 = floorf(py);
      if (ll == 0){ s.sdx[r] = px - fx0; s.sdy[r] = py - fy0; s.sc0[r] = c0; s.sc1[r] = c1; }
      int x0 = (int)fx0 - 3, y0 = (int)fy0 - 3;
      s.u.a.dots[r][ll] = 0.f;
      if (x0 <= 127 && x0 + 7 >= 0){
        int x0c = min(max(x0, 0), WN - 8);
        int sh = x0c - x0;
        int ip = ll >> 3;
        int i = ip + sh;
        bool wr = ((ll & 7) == 0) && (i >= 0) && (i < 8);
        #pragma unroll
        for (int j = 0; j < 8; ++j){
          int yj = y0 + j;
          if (yj < 0 || yj >= HN) continue;
          const u16* blk = fmapT + ((((size_t)t*HN + yj)*WN + x0c) << 6);
          bf16x8 v = *(const bf16x8*)(blk + ll*8);
          float p = 0.f;
          #pragma unroll
          for (int u = 0; u < 8; ++u) p += qv8[u] * b2f16((u16)v[u]);
          p += __shfl_xor(p, 1, 64);
          p += __shfl_xor(p, 2, 64);
          p += __shfl_xor(p, 4, 64);
          if (wr) s.u.a.dots[r][j*8 + i] = p;
        }
      }
    }
  } else {
    for (int rr = 0; rr < 4; ++rr){
      int r = wv*4 + rr, t = T0 + r, grow = q*TN + t;
      float c0 = fixnan(tr_in[2*grow]), c1 = fixnan(tr_in[2*grow+1]);
      float px = fminf(fmaxf(c0 / fs, -1e6f), 1e6f);
      float py = fminf(fmaxf(c1 / fs, -1e6f), 1e6f);
      float fx0 = floorf(px), fy0 = floorf(py);
      if (ll == 0){ s.sdx[r] = px - fx0; s.sdy[r] = py - fy0; s.sc0[r] = c0; s.sc1[r] = c1; }
      int bx = (int)fx0, by = (int)fy0;
      int j = ll >> 3, i = ll & 7;
      int xi = bx + i - 3, yi = by + j - 3;
      float dot = 0.f;
      if (xi >= 0 && xi < WN && yi >= 0 && yi < HN){
        size_t base = ((size_t)t*CN)*HN*WN + (size_t)yi*WN + xi;
        #pragma unroll 8
        for (int c = 0; c < CN; ++c)
          dot += s.qv[c] * ld<MODE>(fmap, base + (size_t)c*HN*WN);
      }
      s.u.a.dots[r][ll] = dot;
    }
  }
  __syncthreads();

  // ---- Phase 2: assemble X ----
  for (int idx = tid; idx < 32*KK; idx += 512){
    int r = idx / KK, kk = idx % KK, oy = kk / 7, ox = kk % 7;
    float dx = s.sdx[r], dy = s.sdy[r];
    const float* dr = s.u.a.dots[r];
    float v = (1.f-dx)*(1.f-dy)*dr[oy*8+ox]     + dx*(1.f-dy)*dr[oy*8+ox+1]
            + (1.f-dx)*dy*dr[(oy+1)*8+ox]       + dx*dy*dr[(oy+1)*8+ox+1];
    bput(&s.u.a.Xs[0][0], 320, r, kk, fixnan(v));
  }
  for (int idx = tid; idx < 32*3; idx += 512){
    int r = idx / 3, cd = idx % 3;
    float v = (cd == 0) ? s.sc0[r] : (cd == 1 ? s.sc1[r] : (float)(T0+r)/(float)(TN-1));
    bput(&s.u.a.Xs[0][0], 320, r, KK + cd, v);
  }
  for (int idx = tid; idx < 32*96; idx += 512){
    int r = idx / 96, j = idx % 96, coord = j >> 5, rm = j & 31, band = rm & 15;
    float cv = (coord == 0) ? s.sc0[r] : (coord == 1 ? s.sc1[r] : (float)(T0+r)/(float)(TN-1));
    float a = cv * exp2f(0.6f*(float)band) * PI_F;
    float v = (rm < 16) ? __sinf(a) : __cosf(a);
    bput(&s.u.a.Xs[0][0], 320, r, KK + 3 + coord*32 + rm, fixnan(v));
  }
  for (int idx = tid; idx < 32*DN; idx += 512){
    int r = idx >> 7, d = idx & 127;
    int grow = q*TN + T0 + r;
    bput(&s.u.a.Xs[0][0], 320, r, 148 + d, fixnan(hd_in[(size_t)grow*DN + d]));
  }
  for (int idx = tid; idx < 32*12; idx += 512){
    int r = idx / 12, p = idx % 12;
    bput(&s.u.a.Xs[0][0], 320, r, IN_DIM + p, 0.f);
  }
  __syncthreads();

  // ---- Phase 3: proj MFMA (A-frags hoisted) ----
  {
    int rA = ll & 15, gK = ll >> 4;
    int rt = wv & 1, nt0 = wv >> 1;
    bf16x8 afr[9];
    #pragma unroll
    for (int ks = 0; ks < 9; ++ks)
      afr[ks] = bget8(&s.u.a.Xs[0][0], 320, rt*16 + rA, ks*32 + gK*8);
    #pragma unroll
    for (int h = 0; h < 2; ++h){
      int nt = nt0 + h*4;
      float bv = ld<MODE>(pb, nt*16 + rA);
      f32x4 acc = {bv, bv, bv, bv};
      #pragma unroll
      for (int ks = 0; ks < 9; ++ks)
        acc = mfma16(afr[ks],
          *(const bf16x8*)((const short*)pwt + (size_t)(nt*16 + rA)*XPAD + ks*32 + gK*8), acc);
      #pragma unroll
      for (int r2 = 0; r2 < 4; ++r2)
        s.hdl[rt*16 + gK*4 + r2][nt*16 + rA] = fixnan(acc[r2]);
    }
  }

  // ---- Phase 4: 4 transformer blocks ----
  int dconv = tid & 127;
  #pragma unroll 1
  for (int L = 0; L < 4; ++L){
    float cwr[5];
    #pragma unroll
    for (int k = 0; k < 5; ++k) cwr[k] = ld<MODE>(cw, ((size_t)L*DN + dconv)*5 + k);
    float cbv = ld<MODE>(cb, L*DN + dconv);
    __syncthreads();
    {
      float g0 = ld<MODE>(ln1g, L*DN + ll), g1 = ld<MODE>(ln1g, L*DN + ll + 64);
      float b0 = ld<MODE>(ln1b, L*DN + ll), b1v = ld<MODE>(ln1b, L*DN + ll + 64);
      #pragma unroll
      for (int rr = 0; rr < 4; ++rr){
        int r = wv*4 + rr;
        float a0 = s.hdl[r][ll], a1 = s.hdl[r][ll+64];
        float m = waveReduceSum(a0 + a1) * (1.f/128.f);
        float v0 = a0 - m, v1 = a1 - m;
        float var = waveReduceSum(v0*v0 + v1*v1) * (1.f/128.f);
        float inv = rsqrtf(var + 1e-5f);
        bput(&s.u.b.hn[0][0], 128, r, ll,      v0*inv*g0 + b0);
        bput(&s.u.b.hn[0][0], 128, r, ll + 64, v1*inv*g1 + b1v);
      }
    }
    __syncthreads();
    for (int idx = tid; idx < 32*DN; idx += 512){
      int r = idx >> 7, t = T0 + r;
      float acc = cbv;
      #pragma unroll
      for (int k = 0; k < 5; ++k){
        int tg = t + k - 2, tl = r + k - 2;
        if (tg >= 0 && tg < TN && tl >= 0 && tl < 32)
          acc += bget(&s.u.b.hn[0][0], 128, tl, dconv) * cwr[k];
      }
      s.hdl[r][dconv] = fixnan(s.hdl[r][dconv] + acc);
    }
    __syncthreads();
    {
      float g0 = ld<MODE>(ln2g, L*DN + ll), g1 = ld<MODE>(ln2g, L*DN + ll + 64);
      float b0 = ld<MODE>(ln2b, L*DN + ll), b1v = ld<MODE>(ln2b, L*DN + ll + 64);
      #pragma unroll
      for (int rr = 0; rr < 4; ++rr){
        int r = wv*4 + rr;
        float a0 = s.hdl[r][ll], a1 = s.hdl[r][ll+64];
        float m = waveReduceSum(a0 + a1) * (1.f/128.f);
        float v0 = a0 - m, v1 = a1 - m;
        float var = waveReduceSum(v0*v0 + v1*v1) * (1.f/128.f);
        float inv = rsqrtf(var + 1e-5f);
        bput(&s.u.b.hn[0][0], 128, r, ll,      v0*inv*g0 + b0);
        bput(&s.u.b.hn[0][0], 128, r, ll + 64, v1*inv*g1 + b1v);
      }
    }
    __syncthreads();
    {
      int rA = ll & 15, gK = ll >> 4;
      int rt = wv & 1, nt0 = wv >> 1;
      const short* w1s = (const short*)w1t + (size_t)L*32768;
      bf16x8 afr[4];
      #pragma unroll
      for (int ks = 0; ks < 4; ++ks)
        afr[ks] = bget8(&s.u.b.hn[0][0], 128, rt*16 + rA, ks*32 + gK*8);
      #pragma unroll
      for (int h = 0; h < 4; ++h){
        int nt = nt0 + h*4;
        float bv = ld<MODE>(b1, L*256 + nt*16 + rA);
        f32x4 acc = {bv, bv, bv, bv};
        #pragma unroll
        for (int ks = 0; ks < 4; ++ks)
          acc = mfma16(afr[ks],
            *(const bf16x8*)(w1s + (size_t)(nt*16 + rA)*DN + ks*32 + gK*8), acc);
        #pragma unroll
        for (int r2 = 0; r2 < 4; ++r2)
          bput(&s.u.b.y1[0][0], 256, rt*16 + gK*4 + r2, nt*16 + rA, gelu_exact(acc[r2]));
      }
    }
    __syncthreads();
    {
      int rA = ll & 15, gK = ll >> 4;
      int rt = wv & 1, nt0 = wv >> 1;
      const short* w2s = (const short*)w2t + (size_t)L*32768;
      bf16x8 afr[8];
      #pragma unroll
      for (int ks = 0; ks < 8; ++ks)
        afr[ks] = bget8(&s.u.b.y1[0][0], 256, rt*16 + rA, ks*32 + gK*8);
      #pragma unroll
      for (int h = 0; h < 2; ++h){
        int nt = nt0 + h*4;
        float bv = ld<MODE>(b2, L*DN + nt*16 + rA);
        f32x4 acc = {bv, bv, bv, bv};
        #pragma unroll
        for (int ks = 0; ks < 8; ++ks)
          acc = mfma16(afr[ks],
            *(const bf16x8*)(w2s + (size_t)(nt*16 + rA)*256 + ks*32 + gK*8), acc);
        #pragma unroll
        for (int r2 = 0; r2 < 4; ++r2){
          int r = rt*16 + gK*4 + r2, cc = nt*16 + rA;
          s.hdl[r][cc] = fixnan(s.hdl[r][cc] + acc[r2]);
        }
      }
    }
  }
  __syncthreads();

  // ---- Phase 5: heads (vis via MFMA) ----
  for (int idx = tid; idx < 32*DN; idx += 512){
    int r = idx >> 7, d = idx & 127;
    bput(&s.u.b.hn[0][0], 128, r, d, s.hdl[r][d]);
  }
  __syncthreads();
  float* gC = (float*)&s.u.b.y1[0][0];   // [32][72] f32
  {
    int rA = ll & 15, gK = ll >> 4;
    int rt = wv & 1, nt = wv >> 1;
    float bv = ld<MODE>(vb1, nt*16 + rA);
    f32x4 acc = {bv, bv, bv, bv};
    #pragma unroll
    for (int ks = 0; ks < 4; ++ks)
      acc = mfma16(bget8(&s.u.b.hn[0][0], 128, rt*16 + rA, ks*32 + gK*8),
                   *(const bf16x8*)((const short*)vw1t + (size_t)(nt*16 + rA)*128 + ks*32 + gK*8), acc);
    #pragma unroll
    for (int r2 = 0; r2 < 4; ++r2)
      gC[(rt*16 + gK*4 + r2)*72 + nt*16 + rA] = gelu_exact(acc[r2]);
  }
  __syncthreads();
  float vw2v = ld<MODE>(vw2, ll);
  float dwa = ld<MODE>(dwp, ll*2),     dwb = ld<MODE>(dwp, (ll+64)*2);
  float dwc = ld<MODE>(dwp, ll*2 + 1), dwd = ld<MODE>(dwp, (ll+64)*2 + 1);
  #pragma unroll
  for (int rr = 0; rr < 4; ++rr){
    int r = wv*4 + rr, t = T0 + r, grow = q*TN + t;
    bool owned = half ? (r >= 8) : (r < 24);
    float vis = waveReduceSum(gC[r*72 + ll] * vw2v);
    float x0 = s.hdl[r][ll], x1 = s.hdl[r][ll+64];
    float dX = waveReduceSum(x0*dwa + x1*dwb);
    float dY = waveReduceSum(x0*dwc + x1*dwd);
    if (owned){
      hd_out[(size_t)grow*DN + ll]      = fixnan(x0);
      hd_out[(size_t)grow*DN + ll + 64] = fixnan(x1);
      if (ll == 0){
        float tx = fixnan(tr_in[2*grow]   + dX + ld<MODE>(dbp, 0));
        float ty = fixnan(tr_in[2*grow+1] + dY + ld<MODE>(dbp, 1));
        tr_out[2*grow] = tx; tr_out[2*grow+1] = ty;
        float vs = fixnan(vi_in[grow] + vis + ld<MODE>(vb2, 0));
        vi_out[grow] = vs;
        if (last){
          if constexpr (MODE == 0){
            ((float*)out)[grow*3 + 0] = tx;
            ((float*)out)[grow*3 + 1] = ty;
            ((float*)out)[grow*3 + 2] = vs * 0.25f;
          } else {
            ((bf16*)out)[grow*3 + 0] = __float2bfloat16(tx);
            ((bf16*)out)[grow*3 + 1] = __float2bfloat16(ty);
            ((bf16*)out)[grow*3 + 2] = __float2bfloat16(vs * 0.25f);
          }
        }
      }
    }
  }
}

template<int FAST>
__global__ __launch_bounds__(512, 2) void k_iter(const int* __restrict__ mf,
    const void* fmap, const u16* fmapT, const void* query, const void* stride_p,
    const float* tr_in, float* tr_out, const float* vi_in, float* vi_out,
    const float* hd_in, float* hd_out,
    const bf16* pwt, const void* pb,
    const void* ln1g, const void* ln1b, const void* cw, const void* cb,
    const void* ln2g, const void* ln2b,
    const bf16* w1t, const void* b1, const bf16* w2t, const void* b2,
    const void* dwp, const void* dbp,
    const bf16* vw1t, const void* vb1, const void* vw2, const void* vb2,
    void* out, int last)
{
  __shared__ SLds s;
  if (mf[0] == 0)
    iter_impl<0, FAST>(s, fmap, fmapT, query, stride_p, tr_in, tr_out, vi_in, vi_out, hd_in, hd_out,
                 pwt, pb, ln1g, ln1b, cw, cb, ln2g, ln2b, w1t, b1, w2t, b2,
                 dwp, dbp, vw1t, vb1, vw2, vb2, out, last);
  else
    iter_impl<1, FAST>(s, fmap, fmapT, query, stride_p, tr_in, tr_out, vi_in, vi_out, hd_in, hd_out,
                 pwt, pb, ln1g, ln1b, cw, cb, ln2g, ln2b, w1t, b1, w2t, b2,
                 dwp, dbp, vw1t, vb1, vw2, vb2, out, last);
}

extern "C" void kernel_launch(void* const* d_in, const int* in_sizes, int n_in,
                              void* d_out, int out_size, void* d_ws, size_t ws_size,
                              hipStream_t stream) {
  const void* ct    = d_in[0];
  const void* query = d_in[1];
  const void* fmap  = d_in[2];
  const void* fs    = d_in[3];
  const void* pw    = d_in[4];
  const void* pb    = d_in[5];
  const void* ln1g  = d_in[6];
  const void* ln1b  = d_in[7];
  const void* cw    = d_in[8];
  const void* cb    = d_in[9];
  const void* ln2g  = d_in[10];
  const void* ln2b  = d_in[11];
  const void* w1    = d_in[12];
  const void* b1    = d_in[13];
  const void* w2    = d_in[14];
  const void* b2    = d_in[15];
  const void* dw    = d_in[16];
  const void* db    = d_in[17];
  const void* vw1   = d_in[18];
  const void* vb1   = d_in[19];
  const void* vw2   = d_in[20];
  const void* vb2   = d_in[21];

  char* w0 = (char*)d_ws;
  char* w = w0;
  int*   mflag = (int*)w;                   w += 256;
  float* tr[2]; float* vi[2]; float* hd[2];
  for (int i = 0; i < 2; ++i){ tr[i] = (float*)w; w += ((size_t)NROWS*2*4 + 255) & ~255ull; }
  for (int i = 0; i < 2; ++i){ vi[i] = (float*)w; w += ((size_t)NROWS*4   + 255) & ~255ull; }
  for (int i = 0; i < 2; ++i){ hd[i] = (float*)w; w += ((size_t)NROWS*DN*4 + 255) & ~255ull; }
  bf16* pwt = (bf16*)w;                     w += ((size_t)128*XPAD*2 + 255) & ~255ull;
  bf16* w1t = (bf16*)w;                     w += ((size_t)4*256*128*2 + 255) & ~255ull;
  bf16* w2t = (bf16*)w;                     w += ((size_t)4*128*256*2 + 255) & ~255ull;
  bf16* vw1t = (bf16*)w;                    w += ((size_t)64*128*2 + 255) & ~255ull;
  u16*  fmapT = (u16*)w;                    w += ((size_t)TN*HN*WN*CN*2 + 255) & ~255ull;

  bool fast = ((size_t)(w - w0) <= ws_size);

  k_sniff<<<1, 256, 0, stream>>>((const unsigned short*)query, mflag);
  hipMemsetAsync(hd[0], 0, (size_t)NROWS*DN*4, stream);

  k_transW<<<(TW_TOT + 255)/256, 256, 0, stream>>>(mflag, pw, w1, w2, vw1, pwt, w1t, w2t, vw1t);
  k_init<<<(NROWS + 255)/256, 256, 0, stream>>>(mflag, ct, tr[0], vi[0]);
  if (fast)
    k_transpose<<<TN*HN, 256, 0, stream>>>(mflag, fmap, fmapT);

  for (int it = 0; it < 4; ++it){
    int a = it & 1, b = a ^ 1;
    if (fast)
      k_iter<1><<<256, 512, 0, stream>>>(mflag, fmap, fmapT, query, fs,
          tr[a], tr[b], vi[a], vi[b], hd[a], hd[b],
          pwt, pb, ln1g, ln1b, cw, cb, ln2g, ln2b,
          w1t, b1, w2t, b2, dw, db, vw1t, vb1, vw2, vb2,
          d_out, it == 3);
    else
      k_iter<0><<<256, 512, 0, stream>>>(mflag, fmap, fmapT, query, fs,
          tr[a], tr[b], vi[a], vi[b], hd[a], hd[b],
          pwt, pb, ln1g, ln1b, cw, cb, ln2g, ln2b,
          w1t, b1, w2t, b2, dw, db, vw1t, vb1, vw2, vb2,
          d_out, it == 3);
  }
}